// Round 3
// baseline (4926.333 us; speedup 1.0000x reference)
//
#include <hip/hip_runtime.h>
#include <hip/hip_bf16.h>
#include <math.h>

// ----------------------------------------------------------------------------
// GEMM: C[M,N] = act( A[M,K] * B[N,K]^T + bias ) (+C if ACC)
// ACT: 0 none, 1 gelu(exact), 2 softplus
// ----------------------------------------------------------------------------
template<int ACT, bool ACC, bool BIAS>
__global__ __launch_bounds__(256)
void gemm_bt(const float* __restrict__ A, const float* __restrict__ B,
             const float* __restrict__ bias, float* __restrict__ C,
             int M, int N, int K, int lda, int ldb, int ldc)
{
    __shared__ alignas(16) float As[16][68];
    __shared__ alignas(16) float Bs[16][68];
    const int tid = threadIdx.x;
    const int m0 = blockIdx.y * 64;
    const int n0 = blockIdx.x * 64;
    const int ty = tid >> 4, tx = tid & 15;
    const int lrow = tid >> 2;          // 0..63
    const int lk   = (tid & 3) << 2;    // 0,4,8,12

    float acc[4][4] = {};

    for (int k0 = 0; k0 < K; k0 += 16) {
        {
            int gr = m0 + lrow;
            float4 v; v.x = v.y = v.z = v.w = 0.f;
            if (gr < M) v = *reinterpret_cast<const float4*>(A + (size_t)gr * lda + k0 + lk);
            As[lk + 0][lrow] = v.x; As[lk + 1][lrow] = v.y;
            As[lk + 2][lrow] = v.z; As[lk + 3][lrow] = v.w;
        }
        {
            int gr = n0 + lrow;
            float4 v; v.x = v.y = v.z = v.w = 0.f;
            if (gr < N) v = *reinterpret_cast<const float4*>(B + (size_t)gr * ldb + k0 + lk);
            Bs[lk + 0][lrow] = v.x; Bs[lk + 1][lrow] = v.y;
            Bs[lk + 2][lrow] = v.z; Bs[lk + 3][lrow] = v.w;
        }
        __syncthreads();
#pragma unroll
        for (int k = 0; k < 16; ++k) {
            float4 a = *reinterpret_cast<const float4*>(&As[k][ty << 2]);
            float4 b = *reinterpret_cast<const float4*>(&Bs[k][tx << 2]);
            acc[0][0] += a.x * b.x; acc[0][1] += a.x * b.y; acc[0][2] += a.x * b.z; acc[0][3] += a.x * b.w;
            acc[1][0] += a.y * b.x; acc[1][1] += a.y * b.y; acc[1][2] += a.y * b.z; acc[1][3] += a.y * b.w;
            acc[2][0] += a.z * b.x; acc[2][1] += a.z * b.y; acc[2][2] += a.z * b.z; acc[2][3] += a.z * b.w;
            acc[3][0] += a.w * b.x; acc[3][1] += a.w * b.y; acc[3][2] += a.w * b.z; acc[3][3] += a.w * b.w;
        }
        __syncthreads();
    }

#pragma unroll
    for (int i = 0; i < 4; ++i) {
        int m = m0 + (ty << 2) + i;
        if (m >= M) continue;
#pragma unroll
        for (int j = 0; j < 4; ++j) {
            int n = n0 + (tx << 2) + j;
            if (n >= N) continue;
            float v = acc[i][j];
            if (BIAS) v += bias[n];
            if (ACT == 1) v = 0.5f * v * (1.0f + erff(v * 0.70710678118654752440f));
            else if (ACT == 2) v = fmaxf(v, 0.f) + log1pf(expf(-fabsf(v)));
            size_t idx = (size_t)m * ldc + n;
            if (ACC) v += C[idx];
            C[idx] = v;
        }
    }
}

// ----------------------------------------------------------------------------
// LayerNorm over last dim (=1024), one row per 256-thread block. fp32 out.
// Safe in-place (outp == x): all reads complete before writes.
// ----------------------------------------------------------------------------
template<bool RES>
__global__ __launch_bounds__(256)
void ln_k(const float* __restrict__ x, const float* __restrict__ res,
          const float* __restrict__ g, const float* __restrict__ b,
          float* __restrict__ outp)
{
    int row = blockIdx.x;
    int t = threadIdx.x;
    float4 v = reinterpret_cast<const float4*>(x + (size_t)row * 1024)[t];
    if (RES) {
        float4 r2 = reinterpret_cast<const float4*>(res + (size_t)row * 1024)[t];
        v.x += r2.x; v.y += r2.y; v.z += r2.z; v.w += r2.w;
    }
    float s  = v.x + v.y + v.z + v.w;
    float ss = v.x * v.x + v.y * v.y + v.z * v.z + v.w * v.w;
#pragma unroll
    for (int off = 32; off > 0; off >>= 1) {
        s  += __shfl_down(s, off, 64);
        ss += __shfl_down(ss, off, 64);
    }
    __shared__ float red[2][4];
    __shared__ float mv[2];
    int wid = t >> 6;
    if ((t & 63) == 0) { red[0][wid] = s; red[1][wid] = ss; }
    __syncthreads();
    if (t == 0) {
        float S  = red[0][0] + red[0][1] + red[0][2] + red[0][3];
        float SS = red[1][0] + red[1][1] + red[1][2] + red[1][3];
        float mean = S * (1.f / 1024.f);
        float var  = SS * (1.f / 1024.f) - mean * mean;
        mv[0] = mean; mv[1] = rsqrtf(var + 1e-5f);
    }
    __syncthreads();
    float mean = mv[0], rstd = mv[1];
    float4 gg = reinterpret_cast<const float4*>(g)[t];
    float4 bb = reinterpret_cast<const float4*>(b)[t];
    float4 ov;
    ov.x = (v.x - mean) * rstd * gg.x + bb.x;
    ov.y = (v.y - mean) * rstd * gg.y + bb.y;
    ov.z = (v.z - mean) * rstd * gg.z + bb.z;
    ov.w = (v.w - mean) * rstd * gg.w + bb.w;
    reinterpret_cast<float4*>(outp + (size_t)row * 1024)[t] = ov;
}

// ----------------------------------------------------------------------------
// Flash attention: grid (B*H*4), block 64 (1 wave); thread = 1 q-row of 64-tile.
// hd=64, LIN=2048, NQ=256, scale=1/8. q shared across batch.
// ----------------------------------------------------------------------------
__global__ __launch_bounds__(64)
void attn_k(const float* __restrict__ qh, const float* __restrict__ kh,
            const float* __restrict__ vh, float* __restrict__ o)
{
    int bx = blockIdx.x;
    int qt = bx & 3;
    int h  = (bx >> 2) & 15;
    int b  = bx >> 6;
    int t  = threadIdx.x;

    __shared__ alignas(16) float ks[32][68];
    __shared__ alignas(16) float vs[32][68];

    float q[64];
    {
        const float* qp = qh + (size_t)(qt * 64 + t) * 1024 + h * 64;
#pragma unroll
        for (int d4 = 0; d4 < 16; ++d4) {
            float4 v = *reinterpret_cast<const float4*>(qp + d4 * 4);
            q[d4 * 4 + 0] = v.x; q[d4 * 4 + 1] = v.y;
            q[d4 * 4 + 2] = v.z; q[d4 * 4 + 3] = v.w;
        }
    }
    float m = -1e30f, l = 0.f;
    float acc[64] = {};
    const float* khb = kh + ((size_t)b * 2048) * 1024 + h * 64;
    const float* vhb = vh + ((size_t)b * 2048) * 1024 + h * 64;

    for (int kt = 0; kt < 2048; kt += 32) {
        __syncthreads();
        {
            int r = t >> 1, p = (t & 1) * 32;
            const float* src = khb + (size_t)(kt + r) * 1024 + p;
#pragma unroll
            for (int d4 = 0; d4 < 8; ++d4)
                *reinterpret_cast<float4*>(&ks[r][p + d4 * 4]) =
                    *reinterpret_cast<const float4*>(src + d4 * 4);
            src = vhb + (size_t)(kt + r) * 1024 + p;
#pragma unroll
            for (int d4 = 0; d4 < 8; ++d4)
                *reinterpret_cast<float4*>(&vs[r][p + d4 * 4]) =
                    *reinterpret_cast<const float4*>(src + d4 * 4);
        }
        __syncthreads();
#pragma unroll 1
        for (int kk = 0; kk < 32; ++kk) {
            float s = 0.f;
#pragma unroll
            for (int d4 = 0; d4 < 16; ++d4) {
                float4 k4 = *reinterpret_cast<const float4*>(&ks[kk][d4 * 4]);
                s += q[d4 * 4 + 0] * k4.x + q[d4 * 4 + 1] * k4.y
                   + q[d4 * 4 + 2] * k4.z + q[d4 * 4 + 3] * k4.w;
            }
            s *= 0.125f;
            if (s > m) {
                float scale = __expf(m - s);
                l = l * scale + 1.f;
                m = s;
#pragma unroll
                for (int d4 = 0; d4 < 16; ++d4) {
                    float4 vv = *reinterpret_cast<const float4*>(&vs[kk][d4 * 4]);
                    acc[d4 * 4 + 0] = acc[d4 * 4 + 0] * scale + vv.x;
                    acc[d4 * 4 + 1] = acc[d4 * 4 + 1] * scale + vv.y;
                    acc[d4 * 4 + 2] = acc[d4 * 4 + 2] * scale + vv.z;
                    acc[d4 * 4 + 3] = acc[d4 * 4 + 3] * scale + vv.w;
                }
            } else {
                float p = __expf(s - m);
                l += p;
#pragma unroll
                for (int d4 = 0; d4 < 16; ++d4) {
                    float4 vv = *reinterpret_cast<const float4*>(&vs[kk][d4 * 4]);
                    acc[d4 * 4 + 0] += p * vv.x;
                    acc[d4 * 4 + 1] += p * vv.y;
                    acc[d4 * 4 + 2] += p * vv.z;
                    acc[d4 * 4 + 3] += p * vv.w;
                }
            }
        }
    }
    float inv = 1.f / l;
    float* op = o + (size_t)(b * 256 + qt * 64 + t) * 1024 + h * 64;
#pragma unroll
    for (int d4 = 0; d4 < 16; ++d4) {
        float4 v;
        v.x = acc[d4 * 4 + 0] * inv; v.y = acc[d4 * 4 + 1] * inv;
        v.z = acc[d4 * 4 + 2] * inv; v.w = acc[d4 * 4 + 3] * inv;
        *reinterpret_cast<float4*>(op + d4 * 4) = v;
    }
}

// hq[r,:] = qln[r%256,:] + oproj[r,:]   (float4 over 1024*256 vec4s)
__global__ void add_bcast_k(const float* __restrict__ q, const float* __restrict__ o,
                            float* __restrict__ hq)
{
    int i = blockIdx.x * 256 + threadIdx.x;
    int r = i >> 8, c = i & 255;
    float4 qv = reinterpret_cast<const float4*>(q)[(r & 255) * 256 + c];
    float4 ov = reinterpret_cast<const float4*>(o)[i];
    float4 s; s.x = qv.x + ov.x; s.y = qv.y + ov.y; s.z = qv.z + ov.z; s.w = qv.w + ov.w;
    reinterpret_cast<float4*>(hq)[i] = s;
}

// causal depthwise conv (K=4) + bias + silu. xin = xz[:, :2048].
__global__ void conv_k(const float* __restrict__ xz, const float* __restrict__ cw,
                       const float* __restrict__ cb, float* __restrict__ xc)
{
    int i = blockIdx.x * 256 + threadIdx.x;   // 0..1024*2048
    int r = i >> 11, c = i & 2047;
    int t = r & 255;
    float a = cb[c];
#pragma unroll
    for (int k = 0; k < 4; ++k) {
        int tt = t - 3 + k;
        if (tt >= 0) a += xz[(size_t)(r - 3 + k) * 4096 + c] * cw[c * 4 + k];
    }
    xc[i] = a / (1.f + expf(-a));
}

// mamba scan: grid (B*8) blocks x 256; thread = one channel c of one batch b.
__global__ __launch_bounds__(256)
void scan_k(const float* __restrict__ delta, const float* __restrict__ dbl,
            const float* __restrict__ xc, const float* __restrict__ Alog,
            float* __restrict__ ys)
{
    int c = (blockIdx.x & 7) * 256 + threadIdx.x;
    int b = blockIdx.x >> 3;
    float A[16], hst[16];
#pragma unroll
    for (int n = 0; n < 16; ++n) { A[n] = -expf(Alog[c * 16 + n]); hst[n] = 0.f; }
    for (int t = 0; t < 256; ++t) {
        int r = b * 256 + t;
        float dt = delta[(size_t)r * 2048 + c];
        float xv = xc[(size_t)r * 2048 + c];
        const float* row = dbl + (size_t)r * 96;
        float dx = dt * xv;
        float y = 0.f;
#pragma unroll
        for (int n = 0; n < 16; ++n) {
            float e = __expf(dt * A[n]);
            hst[n] = e * hst[n] + dx * row[64 + n];
            y += hst[n] * row[80 + n];
        }
        ys[(size_t)r * 2048 + c] = y;
    }
}

// g = (ys + D*xc) * silu(z), z = xz[:, 2048:]
__global__ void gate_k(const float* __restrict__ ys, const float* __restrict__ xc,
                       const float* __restrict__ xz, const float* __restrict__ Dp,
                       float* __restrict__ g)
{
    int i = blockIdx.x * 256 + threadIdx.x;   // float4 idx over 1024*512
    int r = i >> 9, c4 = i & 511;
    float4 y = reinterpret_cast<const float4*>(ys)[i];
    float4 x = reinterpret_cast<const float4*>(xc)[i];
    float4 z = reinterpret_cast<const float4*>(xz)[r * 1024 + 512 + c4];
    float4 d = reinterpret_cast<const float4*>(Dp)[c4];
    float4 o;
    o.x = (y.x + d.x * x.x) * (z.x / (1.f + expf(-z.x)));
    o.y = (y.y + d.y * x.y) * (z.y / (1.f + expf(-z.y)));
    o.z = (y.z + d.z * x.z) * (z.z / (1.f + expf(-z.z)));
    o.w = (y.w + d.w * x.w) * (z.w / (1.f + expf(-z.w)));
    reinterpret_cast<float4*>(g)[i] = o;
}

__global__ void fill_ones_f32(float* p, int n)
{
    int i = blockIdx.x * 256 + threadIdx.x;
    if (i < n) p[i] = 1.0f;
}

extern "C" void kernel_launch(void* const* d_in, const int* in_sizes, int n_in,
                              void* d_out, int out_size, void* d_ws, size_t ws_size,
                              hipStream_t stream)
{
    const float* x      = (const float*)d_in[0];
    const float* W_in   = (const float*)d_in[2];
    const float* b_in   = (const float*)d_in[3];
    const float* latents= (const float*)d_in[4];
    const float* lnq_g  = (const float*)d_in[5];
    const float* lnq_b  = (const float*)d_in[6];
    const float* lnkv_g = (const float*)d_in[7];
    const float* lnkv_b = (const float*)d_in[8];
    const float* W_qkv  = (const float*)d_in[9];
    const float* b_qkv  = (const float*)d_in[10];
    const float* W_o    = (const float*)d_in[11];
    const float* b_o    = (const float*)d_in[12];
    const float* W1     = (const float*)d_in[13];
    const float* b1     = (const float*)d_in[14];
    const float* W2     = (const float*)d_in[15];
    const float* b2     = (const float*)d_in[16];
    const float* lnf_g  = (const float*)d_in[17];
    const float* lnf_b  = (const float*)d_in[18];
    const float* mb_ln_g= (const float*)d_in[19];
    const float* mb_ln_b= (const float*)d_in[20];
    const float* mb_Win = (const float*)d_in[21];
    const float* mb_cw  = (const float*)d_in[22];
    const float* mb_cb  = (const float*)d_in[23];
    const float* mb_xp  = (const float*)d_in[24];
    const float* mb_dtW = (const float*)d_in[25];
    const float* mb_dtb = (const float*)d_in[26];
    const float* mb_Alog= (const float*)d_in[27];
    const float* mb_D   = (const float*)d_in[28];
    const float* mb_Wout= (const float*)d_in[29];
    const float* enc_g  = (const float*)d_in[30];
    const float* enc_b  = (const float*)d_in[31];
    const float* out_g  = (const float*)d_in[32];
    const float* out_b  = (const float*)d_in[33];

    float* W = (float*)d_ws;
    // persistent region (total 115.3 MB high-water)
    float* kvh  = W + 0;          // 8192x1024: h, then LN'd in-place -> kv
    float* kh   = W + 8388608;    // 8192x1024
    float* vh   = W + 16777216;   // 8192x1024
    float* qln  = W + 25165824;   // 256x1024
    float* qh   = W + 25427968;   // 256x1024
    float* o_   = W + 25690112;   // 1024x1024
    float* op   = W + 26738688;   // 1024x1024
    float* hq   = W + 27787264;   // 1024x1024  (persistent through mamba)
    // overlay region [0, 24M floats): ffn + mamba scratch (kvh/kh/vh dead by then)
    float* u_   = W + 0;          // 1024x1024
    float* xz   = W + 1048576;    // 1024x4096
    float* xc   = W + 5242880;    // 1024x2048
    float* dbl  = W + 7340032;    // 1024x96
    float* dly  = W + 7471104;    // 1024x2048
    float* ysb  = W + 9568256;    // 1024x2048
    float* gb   = W + 11665408;   // 1024x2048
    float* ff1  = W + 13762560;   // 1024x2048
    float* tmp  = W + 15859712;   // 1024x1024

    dim3 blk(256);

    // 1. h = x @ W_in^T + b_in
    gemm_bt<0,false,true><<<dim3(16,128),blk,0,stream>>>(x, W_in, b_in, kvh, 8192,1024,512, 512,512,1024);
    // 2. kv = LN(h)  (in-place)
    ln_k<false><<<8192,256,0,stream>>>(kvh, nullptr, lnkv_g, lnkv_b, kvh);
    // 3. qln = LN(latents)  (shared across batch)
    ln_k<false><<<256,256,0,stream>>>(latents, nullptr, lnq_g, lnq_b, qln);
    // 4. qh = qln @ Wq^T + bq
    gemm_bt<0,false,true><<<dim3(16,4),blk,0,stream>>>(qln, W_qkv, b_qkv, qh, 256,1024,1024, 1024,1024,1024);
    // 5. kh = kv @ Wk^T + bk
    gemm_bt<0,false,true><<<dim3(16,128),blk,0,stream>>>(kvh, W_qkv+1048576, b_qkv+1024, kh, 8192,1024,1024, 1024,1024,1024);
    // 6. vh = kv @ Wv^T + bv
    gemm_bt<0,false,true><<<dim3(16,128),blk,0,stream>>>(kvh, W_qkv+2097152, b_qkv+2048, vh, 8192,1024,1024, 1024,1024,1024);
    // 7. attention
    attn_k<<<256,64,0,stream>>>(qh, kh, vh, o_);
    // 8. o proj
    gemm_bt<0,false,true><<<dim3(16,16),blk,0,stream>>>(o_, W_o, b_o, op, 1024,1024,1024, 1024,1024,1024);
    // 9. hq = q + op
    add_bcast_k<<<1024,256,0,stream>>>(qln, op, hq);
    // 10. ff1 = gelu(hq @ W1^T + b1)
    gemm_bt<1,false,true><<<dim3(32,16),blk,0,stream>>>(hq, W1, b1, ff1, 1024,2048,1024, 1024,1024,2048);
    // 11. ff2
    gemm_bt<0,false,true><<<dim3(16,16),blk,0,stream>>>(ff1, W2, b2, tmp, 1024,1024,2048, 2048,2048,1024);
    // 12. hq = LN(hq + ff2)
    ln_k<true><<<1024,256,0,stream>>>(hq, tmp, lnf_g, lnf_b, hq);
    // 13. mamba blocks
    for (int i = 0; i < 4; ++i) {
        ln_k<false><<<1024,256,0,stream>>>(hq, nullptr, mb_ln_g + i*1024, mb_ln_b + i*1024, u_);
        gemm_bt<0,false,false><<<dim3(64,16),blk,0,stream>>>(u_, mb_Win + (size_t)i*4194304, nullptr, xz, 1024,4096,1024, 1024,1024,4096);
        conv_k<<<8192,256,0,stream>>>(xz, mb_cw + i*8192, mb_cb + i*2048, xc);
        gemm_bt<0,false,false><<<dim3(2,16),blk,0,stream>>>(xc, mb_xp + i*196608, nullptr, dbl, 1024,96,2048, 2048,2048,96);
        gemm_bt<2,false,true><<<dim3(32,16),blk,0,stream>>>(dbl, mb_dtW + i*131072, mb_dtb + i*2048, dly, 1024,2048,64, 96,64,2048);
        scan_k<<<32,256,0,stream>>>(dly, dbl, xc, mb_Alog + i*32768, ysb);
        gate_k<<<2048,256,0,stream>>>(ysb, xc, xz, mb_D + i*2048, gb);
        gemm_bt<0,true,false><<<dim3(16,16),blk,0,stream>>>(gb, mb_Wout + (size_t)i*2097152, nullptr, hq, 1024,1024,2048, 2048,2048,1024);
    }
    // 14. hq -> enc LN -> tmp
    ln_k<false><<<1024,256,0,stream>>>(hq, nullptr, enc_g, enc_b, tmp);
    // 15. out LN -> fp32 d_out
    ln_k<false><<<1024,256,0,stream>>>(tmp, nullptr, out_g, out_b, (float*)d_out);
    // 16. comp_mask = ones (fp32)
    fill_ones_f32<<<4,256,0,stream>>>((float*)d_out + 1048576, 1024);
}

// Round 4
// 2330.425 us; speedup vs baseline: 2.1139x; 2.1139x over previous
//
#include <hip/hip_runtime.h>
#include <hip/hip_bf16.h>
#include <math.h>

typedef __attribute__((ext_vector_type(8))) short s16x8;
typedef __attribute__((ext_vector_type(4))) float f32x4;

static __device__ inline unsigned short f2bf(float f) {
    unsigned u = __builtin_bit_cast(unsigned, f);
    u += 0x7fffu + ((u >> 16) & 1u);   // RNE
    return (unsigned short)(u >> 16);
}

// ----------------------------------------------------------------------------
// bf16 MFMA GEMM: C[M,N] = act( A[M,K] * B[N,K]^T + bias ) (+C if ACC)
// 128x128 tile, BK=32, 4 waves (2x2 of 64x64), mfma_f32_16x16x32_bf16.
// M,N multiples of 128; K multiple of 32. A,B fp32 in global, converted
// to bf16 during LDS staging. ACT: 0 none, 1 gelu(exact).
// ----------------------------------------------------------------------------
template<int ACT, bool ACC, bool BIAS>
__global__ __launch_bounds__(256)
void gemm_mfma(const float* __restrict__ A, const float* __restrict__ B,
               const float* __restrict__ bias, float* __restrict__ C,
               int M, int N, int K, int lda, int ldb, int ldc)
{
    // pad to 40 shorts (80B rows): 16B-aligned rows, ~2-way LDS bank aliasing
    __shared__ alignas(16) unsigned short As[128][40];
    __shared__ alignas(16) unsigned short Bs[128][40];

    const int tid = threadIdx.x;
    const int m0 = blockIdx.y * 128;
    const int n0 = blockIdx.x * 128;
    const int l  = tid & 63;
    const int w  = tid >> 6;
    const int wr = w >> 1, wc = w & 1;     // wave grid 2x2
    const int fr = l & 15;                 // frag row (A-row / B-row=C-col)
    const int fk = (l >> 4) * 8;           // k-octet

    const int srow = tid >> 1;             // staging row 0..127
    const int sk8  = (tid & 1) * 8;        // 0 or 8

    f32x4 acc[4][4];
#pragma unroll
    for (int i = 0; i < 4; ++i)
#pragma unroll
        for (int j = 0; j < 4; ++j) acc[i][j] = (f32x4){0.f, 0.f, 0.f, 0.f};

    for (int k0 = 0; k0 < K; k0 += 32) {
#pragma unroll
        for (int p = 0; p < 2; ++p) {
            const int kk = k0 + p * 16 + sk8;
            const int lk = p * 16 + sk8;
            {
                const float4* ap = reinterpret_cast<const float4*>(A + (size_t)(m0 + srow) * lda + kk);
                float4 a0 = ap[0], a1 = ap[1];
                s16x8 v;
                v[0] = (short)f2bf(a0.x); v[1] = (short)f2bf(a0.y);
                v[2] = (short)f2bf(a0.z); v[3] = (short)f2bf(a0.w);
                v[4] = (short)f2bf(a1.x); v[5] = (short)f2bf(a1.y);
                v[6] = (short)f2bf(a1.z); v[7] = (short)f2bf(a1.w);
                *reinterpret_cast<s16x8*>(&As[srow][lk]) = v;
            }
            {
                const float4* bp = reinterpret_cast<const float4*>(B + (size_t)(n0 + srow) * ldb + kk);
                float4 b0 = bp[0], b1 = bp[1];
                s16x8 v;
                v[0] = (short)f2bf(b0.x); v[1] = (short)f2bf(b0.y);
                v[2] = (short)f2bf(b0.z); v[3] = (short)f2bf(b0.w);
                v[4] = (short)f2bf(b1.x); v[5] = (short)f2bf(b1.y);
                v[6] = (short)f2bf(b1.z); v[7] = (short)f2bf(b1.w);
                *reinterpret_cast<s16x8*>(&Bs[srow][lk]) = v;
            }
        }
        __syncthreads();

        s16x8 af[4], bf[4];
#pragma unroll
        for (int mi = 0; mi < 4; ++mi)
            af[mi] = *reinterpret_cast<const s16x8*>(&As[wr * 64 + mi * 16 + fr][fk]);
#pragma unroll
        for (int ni = 0; ni < 4; ++ni)
            bf[ni] = *reinterpret_cast<const s16x8*>(&Bs[wc * 64 + ni * 16 + fr][fk]);
#pragma unroll
        for (int mi = 0; mi < 4; ++mi)
#pragma unroll
            for (int ni = 0; ni < 4; ++ni)
                acc[mi][ni] = __builtin_amdgcn_mfma_f32_16x16x32_bf16(
                    af[mi], bf[ni], acc[mi][ni], 0, 0, 0);
        __syncthreads();
    }

    // epilogue: D lane layout col = l&15, row = (l>>4)*4 + r
#pragma unroll
    for (int mi = 0; mi < 4; ++mi) {
#pragma unroll
        for (int ni = 0; ni < 4; ++ni) {
            const int col = n0 + wc * 64 + ni * 16 + fr;
            float bs = BIAS ? bias[col] : 0.f;
            f32x4 v = acc[mi][ni];
#pragma unroll
            for (int r = 0; r < 4; ++r) {
                const int row = m0 + wr * 64 + mi * 16 + (l >> 4) * 4 + r;
                float val = v[r] + bs;
                if (ACT == 1) val = 0.5f * val * (1.0f + erff(val * 0.70710678118654752440f));
                size_t idx = (size_t)row * ldc + col;
                if (ACC) val += C[idx];
                C[idx] = val;
            }
        }
    }
}

// ----------------------------------------------------------------------------
// fp32 fallback GEMM (small/sensitive): C = act(A*B^T + bias); optional
// K-split with atomicAdd (C must be pre-zeroed). ACT: 0 none, 2 softplus.
// ----------------------------------------------------------------------------
template<int ACT, bool BIAS, bool ATOMIC>
__global__ __launch_bounds__(256)
void gemm_bt(const float* __restrict__ A, const float* __restrict__ B,
             const float* __restrict__ bias, float* __restrict__ C,
             int M, int N, int K, int lda, int ldb, int ldc, int ksplit)
{
    __shared__ alignas(16) float As[16][68];
    __shared__ alignas(16) float Bs[16][68];
    const int tid = threadIdx.x;
    const int m0 = blockIdx.y * 64;
    const int n0 = blockIdx.x * 64;
    const int ty = tid >> 4, tx = tid & 15;
    const int lrow = tid >> 2;
    const int lk   = (tid & 3) << 2;

    float acc[4][4] = {};
    const int kbeg = blockIdx.z * ksplit;
    const int kend = kbeg + ksplit;

    for (int k0 = kbeg; k0 < kend; k0 += 16) {
        {
            int gr = m0 + lrow;
            float4 v; v.x = v.y = v.z = v.w = 0.f;
            if (gr < M) v = *reinterpret_cast<const float4*>(A + (size_t)gr * lda + k0 + lk);
            As[lk + 0][lrow] = v.x; As[lk + 1][lrow] = v.y;
            As[lk + 2][lrow] = v.z; As[lk + 3][lrow] = v.w;
        }
        {
            int gr = n0 + lrow;
            float4 v; v.x = v.y = v.z = v.w = 0.f;
            if (gr < N) v = *reinterpret_cast<const float4*>(B + (size_t)gr * ldb + k0 + lk);
            Bs[lk + 0][lrow] = v.x; Bs[lk + 1][lrow] = v.y;
            Bs[lk + 2][lrow] = v.z; Bs[lk + 3][lrow] = v.w;
        }
        __syncthreads();
#pragma unroll
        for (int k = 0; k < 16; ++k) {
            float4 a = *reinterpret_cast<const float4*>(&As[k][ty << 2]);
            float4 b = *reinterpret_cast<const float4*>(&Bs[k][tx << 2]);
            acc[0][0] += a.x * b.x; acc[0][1] += a.x * b.y; acc[0][2] += a.x * b.z; acc[0][3] += a.x * b.w;
            acc[1][0] += a.y * b.x; acc[1][1] += a.y * b.y; acc[1][2] += a.y * b.z; acc[1][3] += a.y * b.w;
            acc[2][0] += a.z * b.x; acc[2][1] += a.z * b.y; acc[2][2] += a.z * b.z; acc[2][3] += a.z * b.w;
            acc[3][0] += a.w * b.x; acc[3][1] += a.w * b.y; acc[3][2] += a.w * b.z; acc[3][3] += a.w * b.w;
        }
        __syncthreads();
    }

#pragma unroll
    for (int i = 0; i < 4; ++i) {
        int m = m0 + (ty << 2) + i;
        if (m >= M) continue;
#pragma unroll
        for (int j = 0; j < 4; ++j) {
            int n = n0 + (tx << 2) + j;
            if (n >= N) continue;
            float v = acc[i][j];
            if (BIAS && blockIdx.z == 0) v += bias[n];
            if (ACT == 2) v = fmaxf(v, 0.f) + log1pf(expf(-fabsf(v)));
            size_t idx = (size_t)m * ldc + n;
            if (ATOMIC) atomicAdd(&C[idx], v);
            else C[idx] = v;
        }
    }
}

// ----------------------------------------------------------------------------
// LayerNorm over last dim (=1024), one row per 256-thread block. fp32.
// ----------------------------------------------------------------------------
template<bool RES>
__global__ __launch_bounds__(256)
void ln_k(const float* __restrict__ x, const float* __restrict__ res,
          const float* __restrict__ g, const float* __restrict__ b,
          float* __restrict__ outp)
{
    int row = blockIdx.x;
    int t = threadIdx.x;
    float4 v = reinterpret_cast<const float4*>(x + (size_t)row * 1024)[t];
    if (RES) {
        float4 r2 = reinterpret_cast<const float4*>(res + (size_t)row * 1024)[t];
        v.x += r2.x; v.y += r2.y; v.z += r2.z; v.w += r2.w;
    }
    float s  = v.x + v.y + v.z + v.w;
    float ss = v.x * v.x + v.y * v.y + v.z * v.z + v.w * v.w;
#pragma unroll
    for (int off = 32; off > 0; off >>= 1) {
        s  += __shfl_down(s, off, 64);
        ss += __shfl_down(ss, off, 64);
    }
    __shared__ float red[2][4];
    __shared__ float mv[2];
    int wid = t >> 6;
    if ((t & 63) == 0) { red[0][wid] = s; red[1][wid] = ss; }
    __syncthreads();
    if (t == 0) {
        float S  = red[0][0] + red[0][1] + red[0][2] + red[0][3];
        float SS = red[1][0] + red[1][1] + red[1][2] + red[1][3];
        float mean = S * (1.f / 1024.f);
        float var  = SS * (1.f / 1024.f) - mean * mean;
        mv[0] = mean; mv[1] = rsqrtf(var + 1e-5f);
    }
    __syncthreads();
    float mean = mv[0], rstd = mv[1];
    float4 gg = reinterpret_cast<const float4*>(g)[t];
    float4 bb = reinterpret_cast<const float4*>(b)[t];
    float4 ov;
    ov.x = (v.x - mean) * rstd * gg.x + bb.x;
    ov.y = (v.y - mean) * rstd * gg.y + bb.y;
    ov.z = (v.z - mean) * rstd * gg.z + bb.z;
    ov.w = (v.w - mean) * rstd * gg.w + bb.w;
    reinterpret_cast<float4*>(outp + (size_t)row * 1024)[t] = ov;
}

// ----------------------------------------------------------------------------
// Flash attention, KV-split partials. grid 2048 = (b,h,qt,split); block 64.
// Each block: 256 KV rows; writes unnormalized acc + (m,l).
// ----------------------------------------------------------------------------
__global__ __launch_bounds__(64)
void attn_part_k(const float* __restrict__ qh, const float* __restrict__ kh,
                 const float* __restrict__ vh, float* __restrict__ pacc,
                 float* __restrict__ pml)
{
    int bx = blockIdx.x;
    int split = bx & 7;
    int qt = (bx >> 3) & 3;
    int h  = (bx >> 5) & 15;
    int b  = bx >> 9;
    int t  = threadIdx.x;

    __shared__ alignas(16) float ks[32][68];
    __shared__ alignas(16) float vs[32][68];

    float q[64];
    {
        const float* qp = qh + (size_t)(qt * 64 + t) * 1024 + h * 64;
#pragma unroll
        for (int d4 = 0; d4 < 16; ++d4) {
            float4 v = *reinterpret_cast<const float4*>(qp + d4 * 4);
            q[d4 * 4 + 0] = v.x; q[d4 * 4 + 1] = v.y;
            q[d4 * 4 + 2] = v.z; q[d4 * 4 + 3] = v.w;
        }
    }
    float m = -1e30f, l = 0.f;
    float acc[64] = {};
    const float* khb = kh + ((size_t)b * 2048) * 1024 + h * 64;
    const float* vhb = vh + ((size_t)b * 2048) * 1024 + h * 64;

    const int kt0 = split * 256;
    for (int kt = kt0; kt < kt0 + 256; kt += 32) {
        __syncthreads();
        {
            int r = t >> 1, p = (t & 1) * 32;
            const float* src = khb + (size_t)(kt + r) * 1024 + p;
#pragma unroll
            for (int d4 = 0; d4 < 8; ++d4)
                *reinterpret_cast<float4*>(&ks[r][p + d4 * 4]) =
                    *reinterpret_cast<const float4*>(src + d4 * 4);
            src = vhb + (size_t)(kt + r) * 1024 + p;
#pragma unroll
            for (int d4 = 0; d4 < 8; ++d4)
                *reinterpret_cast<float4*>(&vs[r][p + d4 * 4]) =
                    *reinterpret_cast<const float4*>(src + d4 * 4);
        }
        __syncthreads();
#pragma unroll 1
        for (int kk = 0; kk < 32; ++kk) {
            float s = 0.f;
#pragma unroll
            for (int d4 = 0; d4 < 16; ++d4) {
                float4 k4 = *reinterpret_cast<const float4*>(&ks[kk][d4 * 4]);
                s += q[d4 * 4 + 0] * k4.x + q[d4 * 4 + 1] * k4.y
                   + q[d4 * 4 + 2] * k4.z + q[d4 * 4 + 3] * k4.w;
            }
            s *= 0.125f;
            if (s > m) {
                float scale = __expf(m - s);
                l = l * scale + 1.f;
                m = s;
#pragma unroll
                for (int d4 = 0; d4 < 16; ++d4) {
                    float4 vv = *reinterpret_cast<const float4*>(&vs[kk][d4 * 4]);
                    acc[d4 * 4 + 0] = acc[d4 * 4 + 0] * scale + vv.x;
                    acc[d4 * 4 + 1] = acc[d4 * 4 + 1] * scale + vv.y;
                    acc[d4 * 4 + 2] = acc[d4 * 4 + 2] * scale + vv.z;
                    acc[d4 * 4 + 3] = acc[d4 * 4 + 3] * scale + vv.w;
                }
            } else {
                float p = __expf(s - m);
                l += p;
#pragma unroll
                for (int d4 = 0; d4 < 16; ++d4) {
                    float4 vv = *reinterpret_cast<const float4*>(&vs[kk][d4 * 4]);
                    acc[d4 * 4 + 0] += p * vv.x;
                    acc[d4 * 4 + 1] += p * vv.y;
                    acc[d4 * 4 + 2] += p * vv.z;
                    acc[d4 * 4 + 3] += p * vv.w;
                }
            }
        }
    }
    int rowid = ((b * 16 + h) * 4 + qt) * 64 + t;
    float* pa = pacc + ((size_t)split * 16384 + rowid) * 64;
#pragma unroll
    for (int d4 = 0; d4 < 16; ++d4) {
        float4 v;
        v.x = acc[d4 * 4 + 0]; v.y = acc[d4 * 4 + 1];
        v.z = acc[d4 * 4 + 2]; v.w = acc[d4 * 4 + 3];
        *reinterpret_cast<float4*>(pa + d4 * 4) = v;
    }
    pml[((size_t)split * 16384 + rowid) * 2 + 0] = m;
    pml[((size_t)split * 16384 + rowid) * 2 + 1] = l;
}

// combine 8 partials per q-row -> o
__global__ __launch_bounds__(64)
void attn_comb_k(const float* __restrict__ pacc, const float* __restrict__ pml,
                 float* __restrict__ o)
{
    int row = blockIdx.x * 64 + threadIdx.x;   // 0..16383
    float M = -1e30f;
#pragma unroll
    for (int s = 0; s < 8; ++s)
        M = fmaxf(M, pml[((size_t)s * 16384 + row) * 2]);
    float L = 0.f;
    float out[64] = {};
#pragma unroll 1
    for (int s = 0; s < 8; ++s) {
        float ms = pml[((size_t)s * 16384 + row) * 2 + 0];
        float ls = pml[((size_t)s * 16384 + row) * 2 + 1];
        float wgt = __expf(ms - M);
        L += wgt * ls;
        const float4* ap = reinterpret_cast<const float4*>(pacc + ((size_t)s * 16384 + row) * 64);
#pragma unroll
        for (int d4 = 0; d4 < 16; ++d4) {
            float4 a = ap[d4];
            out[d4 * 4 + 0] += wgt * a.x; out[d4 * 4 + 1] += wgt * a.y;
            out[d4 * 4 + 2] += wgt * a.z; out[d4 * 4 + 3] += wgt * a.w;
        }
    }
    float inv = 1.f / L;
    int t = row & 63, qt = (row >> 6) & 3, h = (row >> 8) & 15, b = row >> 12;
    float* op = o + (size_t)(b * 256 + qt * 64 + t) * 1024 + h * 64;
#pragma unroll
    for (int d4 = 0; d4 < 16; ++d4) {
        float4 v;
        v.x = out[d4 * 4 + 0] * inv; v.y = out[d4 * 4 + 1] * inv;
        v.z = out[d4 * 4 + 2] * inv; v.w = out[d4 * 4 + 3] * inv;
        *reinterpret_cast<float4*>(op + d4 * 4) = v;
    }
}

// hq[r,:] = qln[r%256,:] + oproj[r,:]
__global__ void add_bcast_k(const float* __restrict__ q, const float* __restrict__ o,
                            float* __restrict__ hq)
{
    int i = blockIdx.x * 256 + threadIdx.x;
    int r = i >> 8, c = i & 255;
    float4 qv = reinterpret_cast<const float4*>(q)[(r & 255) * 256 + c];
    float4 ov = reinterpret_cast<const float4*>(o)[i];
    float4 s; s.x = qv.x + ov.x; s.y = qv.y + ov.y; s.z = qv.z + ov.z; s.w = qv.w + ov.w;
    reinterpret_cast<float4*>(hq)[i] = s;
}

// causal depthwise conv (K=4) + bias + silu
__global__ void conv_k(const float* __restrict__ xz, const float* __restrict__ cw,
                       const float* __restrict__ cb, float* __restrict__ xc)
{
    int i = blockIdx.x * 256 + threadIdx.x;
    int r = i >> 11, c = i & 2047;
    int t = r & 255;
    float a = cb[c];
#pragma unroll
    for (int k = 0; k < 4; ++k) {
        int tt = t - 3 + k;
        if (tt >= 0) a += xz[(size_t)(r - 3 + k) * 4096 + c] * cw[c * 4 + k];
    }
    xc[i] = a / (1.f + expf(-a));
}

// mamba scan
__global__ __launch_bounds__(256)
void scan_k(const float* __restrict__ delta, const float* __restrict__ dbl,
            const float* __restrict__ xc, const float* __restrict__ Alog,
            float* __restrict__ ys)
{
    int c = (blockIdx.x & 7) * 256 + threadIdx.x;
    int b = blockIdx.x >> 3;
    float A[16], hst[16];
#pragma unroll
    for (int n = 0; n < 16; ++n) { A[n] = -expf(Alog[c * 16 + n]); hst[n] = 0.f; }
    for (int t = 0; t < 256; ++t) {
        int r = b * 256 + t;
        float dt = delta[(size_t)r * 2048 + c];
        float xv = xc[(size_t)r * 2048 + c];
        const float* row = dbl + (size_t)r * 96;
        float dx = dt * xv;
        float y = 0.f;
#pragma unroll
        for (int n = 0; n < 16; ++n) {
            float e = __expf(dt * A[n]);
            hst[n] = e * hst[n] + dx * row[64 + n];
            y += hst[n] * row[80 + n];
        }
        ys[(size_t)r * 2048 + c] = y;
    }
}

// g = (ys + D*xc) * silu(z)
__global__ void gate_k(const float* __restrict__ ys, const float* __restrict__ xc,
                       const float* __restrict__ xz, const float* __restrict__ Dp,
                       float* __restrict__ g)
{
    int i = blockIdx.x * 256 + threadIdx.x;
    int r = i >> 9, c4 = i & 511;
    float4 y = reinterpret_cast<const float4*>(ys)[i];
    float4 x = reinterpret_cast<const float4*>(xc)[i];
    float4 z = reinterpret_cast<const float4*>(xz)[r * 1024 + 512 + c4];
    float4 d = reinterpret_cast<const float4*>(Dp)[c4];
    float4 o;
    o.x = (y.x + d.x * x.x) * (z.x / (1.f + expf(-z.x)));
    o.y = (y.y + d.y * x.y) * (z.y / (1.f + expf(-z.y)));
    o.z = (y.z + d.z * x.z) * (z.z / (1.f + expf(-z.z)));
    o.w = (y.w + d.w * x.w) * (z.w / (1.f + expf(-z.w)));
    reinterpret_cast<float4*>(g)[i] = o;
}

__global__ void fill_ones_f32(float* p, int n)
{
    int i = blockIdx.x * 256 + threadIdx.x;
    if (i < n) p[i] = 1.0f;
}

__global__ void fill_zero_f32(float* p, int n)
{
    int i = blockIdx.x * 256 + threadIdx.x;
    if (i < n) p[i] = 0.0f;
}

extern "C" void kernel_launch(void* const* d_in, const int* in_sizes, int n_in,
                              void* d_out, int out_size, void* d_ws, size_t ws_size,
                              hipStream_t stream)
{
    const float* x      = (const float*)d_in[0];
    const float* W_in   = (const float*)d_in[2];
    const float* b_in   = (const float*)d_in[3];
    const float* latents= (const float*)d_in[4];
    const float* lnq_g  = (const float*)d_in[5];
    const float* lnq_b  = (const float*)d_in[6];
    const float* lnkv_g = (const float*)d_in[7];
    const float* lnkv_b = (const float*)d_in[8];
    const float* W_qkv  = (const float*)d_in[9];
    const float* b_qkv  = (const float*)d_in[10];
    const float* W_o    = (const float*)d_in[11];
    const float* b_o    = (const float*)d_in[12];
    const float* W1     = (const float*)d_in[13];
    const float* b1     = (const float*)d_in[14];
    const float* W2     = (const float*)d_in[15];
    const float* b2     = (const float*)d_in[16];
    const float* lnf_g  = (const float*)d_in[17];
    const float* lnf_b  = (const float*)d_in[18];
    const float* mb_ln_g= (const float*)d_in[19];
    const float* mb_ln_b= (const float*)d_in[20];
    const float* mb_Win = (const float*)d_in[21];
    const float* mb_cw  = (const float*)d_in[22];
    const float* mb_cb  = (const float*)d_in[23];
    const float* mb_xp  = (const float*)d_in[24];
    const float* mb_dtW = (const float*)d_in[25];
    const float* mb_dtb = (const float*)d_in[26];
    const float* mb_Alog= (const float*)d_in[27];
    const float* mb_D   = (const float*)d_in[28];
    const float* mb_Wout= (const float*)d_in[29];
    const float* enc_g  = (const float*)d_in[30];
    const float* enc_b  = (const float*)d_in[31];
    const float* out_g  = (const float*)d_in[32];
    const float* out_b  = (const float*)d_in[33];

    float* W = (float*)d_ws;
    // persistent region
    float* kvh  = W + 0;          // 8192x1024: h -> LN in place -> kv; later attn pacc
    float* kh   = W + 8388608;    // 8192x1024
    float* vh   = W + 16777216;   // 8192x1024
    float* qln  = W + 25165824;   // 256x1024
    float* qh   = W + 25427968;   // 256x1024
    float* o_   = W + 25690112;   // 1024x1024
    float* op   = W + 26738688;   // 1024x1024 (pml during attn, then o-proj out)
    float* hq   = W + 27787264;   // 1024x1024
    // overlay region (kvh/kh/vh dead by FFN/mamba time)
    float* u_   = W + 0;          // 1024x1024
    float* xz   = W + 1048576;    // 1024x4096
    float* xc   = W + 5242880;    // 1024x2048
    float* dbl  = W + 7340032;    // 1024x96 (rounded region)
    float* dly  = W + 7471104;    // 1024x2048
    float* ysb  = W + 9568256;    // 1024x2048
    float* gb   = W + 11665408;   // 1024x2048
    float* ff1  = W + 13762560;   // 1024x2048
    float* tmp  = W + 15859712;   // 1024x1024
    // attn partials
    float* pacc = kvh;            // 8*16384*64 = 8388608 floats exactly
    float* pml  = op;             // 8*16384*2  = 262144 floats

    dim3 blk(256);

    // 1. h = x @ W_in^T + b_in            [8192,1024,512]
    gemm_mfma<0,false,true><<<dim3(8,64),blk,0,stream>>>(x, W_in, b_in, kvh, 8192,1024,512, 512,512,1024);
    // 2. kv = LN(h) in place
    ln_k<false><<<8192,256,0,stream>>>(kvh, nullptr, lnkv_g, lnkv_b, kvh);
    // 3. qln = LN(latents)
    ln_k<false><<<256,256,0,stream>>>(latents, nullptr, lnq_g, lnq_b, qln);
    // 4. qh = qln @ Wq^T + bq             [256,1024,1024]
    gemm_mfma<0,false,true><<<dim3(8,2),blk,0,stream>>>(qln, W_qkv, b_qkv, qh, 256,1024,1024, 1024,1024,1024);
    // 5. kh = kv @ Wk^T + bk              [8192,1024,1024]
    gemm_mfma<0,false,true><<<dim3(8,64),blk,0,stream>>>(kvh, W_qkv+1048576, b_qkv+1024, kh, 8192,1024,1024, 1024,1024,1024);
    // 6. vh = kv @ Wv^T + bv
    gemm_mfma<0,false,true><<<dim3(8,64),blk,0,stream>>>(kvh, W_qkv+2097152, b_qkv+2048, vh, 8192,1024,1024, 1024,1024,1024);
    // 7. attention (8-way KV split + combine)
    attn_part_k<<<2048,64,0,stream>>>(qh, kh, vh, pacc, pml);
    attn_comb_k<<<256,64,0,stream>>>(pacc, pml, o_);
    // 8. o proj                           [1024,1024,1024]
    gemm_mfma<0,false,true><<<dim3(8,8),blk,0,stream>>>(o_, W_o, b_o, op, 1024,1024,1024, 1024,1024,1024);
    // 9. hq = q + op
    add_bcast_k<<<1024,256,0,stream>>>(qln, op, hq);
    // 10. ff1 = gelu(hq @ W1^T + b1)      [1024,2048,1024]
    gemm_mfma<1,false,true><<<dim3(16,8),blk,0,stream>>>(hq, W1, b1, ff1, 1024,2048,1024, 1024,1024,2048);
    // 11. ff2                             [1024,1024,2048]
    gemm_mfma<0,false,true><<<dim3(8,8),blk,0,stream>>>(ff1, W2, b2, tmp, 1024,1024,2048, 2048,2048,1024);
    // 12. hq = LN(hq + ff2)
    ln_k<true><<<1024,256,0,stream>>>(hq, tmp, lnf_g, lnf_b, hq);
    // 13. mamba blocks
    for (int i = 0; i < 4; ++i) {
        ln_k<false><<<1024,256,0,stream>>>(hq, nullptr, mb_ln_g + i*1024, mb_ln_b + i*1024, u_);
        // xz = u @ Win^T                  [1024,4096,1024]
        gemm_mfma<0,false,false><<<dim3(32,8),blk,0,stream>>>(u_, mb_Win + (size_t)i*4194304, nullptr, xz, 1024,4096,1024, 1024,1024,4096);
        conv_k<<<8192,256,0,stream>>>(xz, mb_cw + i*8192, mb_cb + i*2048, xc);
        // dbl = xc @ xp^T  (fp32, K-split x8, atomic)
        fill_zero_f32<<<384,256,0,stream>>>(dbl, 98304);
        gemm_bt<0,false,true><<<dim3(2,16,8),blk,0,stream>>>(xc, mb_xp + i*196608, nullptr, dbl, 1024,96,2048, 2048,2048,96, 256);
        // dly = softplus(dtr @ dtW^T + dtb)  (fp32)
        gemm_bt<2,true,false><<<dim3(32,16,1),blk,0,stream>>>(dbl, mb_dtW + i*131072, mb_dtb + i*2048, dly, 1024,2048,64, 96,64,2048, 64);
        scan_k<<<32,256,0,stream>>>(dly, dbl, xc, mb_Alog + i*32768, ysb);
        gate_k<<<2048,256,0,stream>>>(ysb, xc, xz, mb_D + i*2048, gb);
        // hq += g @ Wout^T                [1024,1024,2048]
        gemm_mfma<0,true,false><<<dim3(8,8),blk,0,stream>>>(gb, mb_Wout + (size_t)i*2097152, nullptr, hq, 1024,1024,2048, 2048,2048,1024);
    }
    // 14. enc LN
    ln_k<false><<<1024,256,0,stream>>>(hq, nullptr, enc_g, enc_b, tmp);
    // 15. out LN -> fp32 d_out
    ln_k<false><<<1024,256,0,stream>>>(tmp, nullptr, out_g, out_b, (float*)d_out);
    // 16. comp_mask = ones
    fill_ones_f32<<<4,256,0,stream>>>((float*)d_out + 1048576, 1024);
}

// Round 5
// 1900.647 us; speedup vs baseline: 2.5919x; 1.2261x over previous
//
#include <hip/hip_runtime.h>
#include <hip/hip_bf16.h>
#include <math.h>

typedef __attribute__((ext_vector_type(8))) short s16x8;
typedef __attribute__((ext_vector_type(4))) float f32x4;

static __device__ inline unsigned short f2bf(float f) {
    unsigned u = __builtin_bit_cast(unsigned, f);
    u += 0x7fffu + ((u >> 16) & 1u);   // RNE
    return (unsigned short)(u >> 16);
}

// ----------------------------------------------------------------------------
// bf16 MFMA GEMM: C[M,N] = act( A[M,K] * B[N,K]^T + bias ) (+C if ACC)
// 128x128 tile, BK=32, 4 waves (2x2 of 64x64), mfma_f32_16x16x32_bf16.
// ----------------------------------------------------------------------------
template<int ACT, bool ACC, bool BIAS>
__global__ __launch_bounds__(256)
void gemm_mfma(const float* __restrict__ A, const float* __restrict__ B,
               const float* __restrict__ bias, float* __restrict__ C,
               int M, int N, int K, int lda, int ldb, int ldc)
{
    __shared__ alignas(16) unsigned short As[128][40];
    __shared__ alignas(16) unsigned short Bs[128][40];

    const int tid = threadIdx.x;
    const int m0 = blockIdx.y * 128;
    const int n0 = blockIdx.x * 128;
    const int l  = tid & 63;
    const int w  = tid >> 6;
    const int wr = w >> 1, wc = w & 1;
    const int fr = l & 15;
    const int fk = (l >> 4) * 8;

    const int srow = tid >> 1;
    const int sk8  = (tid & 1) * 8;

    f32x4 acc[4][4];
#pragma unroll
    for (int i = 0; i < 4; ++i)
#pragma unroll
        for (int j = 0; j < 4; ++j) acc[i][j] = (f32x4){0.f, 0.f, 0.f, 0.f};

    for (int k0 = 0; k0 < K; k0 += 32) {
#pragma unroll
        for (int p = 0; p < 2; ++p) {
            const int kk = k0 + p * 16 + sk8;
            const int lk = p * 16 + sk8;
            {
                const float4* ap = reinterpret_cast<const float4*>(A + (size_t)(m0 + srow) * lda + kk);
                float4 a0 = ap[0], a1 = ap[1];
                s16x8 v;
                v[0] = (short)f2bf(a0.x); v[1] = (short)f2bf(a0.y);
                v[2] = (short)f2bf(a0.z); v[3] = (short)f2bf(a0.w);
                v[4] = (short)f2bf(a1.x); v[5] = (short)f2bf(a1.y);
                v[6] = (short)f2bf(a1.z); v[7] = (short)f2bf(a1.w);
                *reinterpret_cast<s16x8*>(&As[srow][lk]) = v;
            }
            {
                const float4* bp = reinterpret_cast<const float4*>(B + (size_t)(n0 + srow) * ldb + kk);
                float4 b0 = bp[0], b1 = bp[1];
                s16x8 v;
                v[0] = (short)f2bf(b0.x); v[1] = (short)f2bf(b0.y);
                v[2] = (short)f2bf(b0.z); v[3] = (short)f2bf(b0.w);
                v[4] = (short)f2bf(b1.x); v[5] = (short)f2bf(b1.y);
                v[6] = (short)f2bf(b1.z); v[7] = (short)f2bf(b1.w);
                *reinterpret_cast<s16x8*>(&Bs[srow][lk]) = v;
            }
        }
        __syncthreads();

        s16x8 af[4], bfg[4];
#pragma unroll
        for (int mi = 0; mi < 4; ++mi)
            af[mi] = *reinterpret_cast<const s16x8*>(&As[wr * 64 + mi * 16 + fr][fk]);
#pragma unroll
        for (int ni = 0; ni < 4; ++ni)
            bfg[ni] = *reinterpret_cast<const s16x8*>(&Bs[wc * 64 + ni * 16 + fr][fk]);
#pragma unroll
        for (int mi = 0; mi < 4; ++mi)
#pragma unroll
            for (int ni = 0; ni < 4; ++ni)
                acc[mi][ni] = __builtin_amdgcn_mfma_f32_16x16x32_bf16(
                    af[mi], bfg[ni], acc[mi][ni], 0, 0, 0);
        __syncthreads();
    }

#pragma unroll
    for (int mi = 0; mi < 4; ++mi) {
#pragma unroll
        for (int ni = 0; ni < 4; ++ni) {
            const int col = n0 + wc * 64 + ni * 16 + fr;
            float bs = BIAS ? bias[col] : 0.f;
            f32x4 v = acc[mi][ni];
#pragma unroll
            for (int r = 0; r < 4; ++r) {
                const int row = m0 + wr * 64 + mi * 16 + (l >> 4) * 4 + r;
                float val = v[r] + bs;
                if (ACT == 1) val = 0.5f * val * (1.0f + erff(val * 0.70710678118654752440f));
                size_t idx = (size_t)row * ldc + col;
                if (ACC) val += C[idx];
                C[idx] = val;
            }
        }
    }
}

// ----------------------------------------------------------------------------
// fp32 GEMM (small/sensitive): C = act(A*B^T + bias); optional K-split atomic.
// ----------------------------------------------------------------------------
template<int ACT, bool BIAS, bool ATOMIC>
__global__ __launch_bounds__(256)
void gemm_bt(const float* __restrict__ A, const float* __restrict__ B,
             const float* __restrict__ bias, float* __restrict__ C,
             int M, int N, int K, int lda, int ldb, int ldc, int ksplit)
{
    __shared__ alignas(16) float As[16][68];
    __shared__ alignas(16) float Bs[16][68];
    const int tid = threadIdx.x;
    const int m0 = blockIdx.y * 64;
    const int n0 = blockIdx.x * 64;
    const int ty = tid >> 4, tx = tid & 15;
    const int lrow = tid >> 2;
    const int lk   = (tid & 3) << 2;

    float acc[4][4] = {};
    const int kbeg = blockIdx.z * ksplit;
    const int kend = kbeg + ksplit;

    for (int k0 = kbeg; k0 < kend; k0 += 16) {
        {
            int gr = m0 + lrow;
            float4 v; v.x = v.y = v.z = v.w = 0.f;
            if (gr < M) v = *reinterpret_cast<const float4*>(A + (size_t)gr * lda + k0 + lk);
            As[lk + 0][lrow] = v.x; As[lk + 1][lrow] = v.y;
            As[lk + 2][lrow] = v.z; As[lk + 3][lrow] = v.w;
        }
        {
            int gr = n0 + lrow;
            float4 v; v.x = v.y = v.z = v.w = 0.f;
            if (gr < N) v = *reinterpret_cast<const float4*>(B + (size_t)gr * ldb + k0 + lk);
            Bs[lk + 0][lrow] = v.x; Bs[lk + 1][lrow] = v.y;
            Bs[lk + 2][lrow] = v.z; Bs[lk + 3][lrow] = v.w;
        }
        __syncthreads();
#pragma unroll
        for (int k = 0; k < 16; ++k) {
            float4 a = *reinterpret_cast<const float4*>(&As[k][ty << 2]);
            float4 b = *reinterpret_cast<const float4*>(&Bs[k][tx << 2]);
            acc[0][0] += a.x * b.x; acc[0][1] += a.x * b.y; acc[0][2] += a.x * b.z; acc[0][3] += a.x * b.w;
            acc[1][0] += a.y * b.x; acc[1][1] += a.y * b.y; acc[1][2] += a.y * b.z; acc[1][3] += a.y * b.w;
            acc[2][0] += a.z * b.x; acc[2][1] += a.z * b.y; acc[2][2] += a.z * b.z; acc[2][3] += a.z * b.w;
            acc[3][0] += a.w * b.x; acc[3][1] += a.w * b.y; acc[3][2] += a.w * b.z; acc[3][3] += a.w * b.w;
        }
        __syncthreads();
    }

#pragma unroll
    for (int i = 0; i < 4; ++i) {
        int m = m0 + (ty << 2) + i;
        if (m >= M) continue;
#pragma unroll
        for (int j = 0; j < 4; ++j) {
            int n = n0 + (tx << 2) + j;
            if (n >= N) continue;
            float v = acc[i][j];
            if (BIAS && blockIdx.z == 0) v += bias[n];
            if (ACT == 2) v = fmaxf(v, 0.f) + log1pf(expf(-fabsf(v)));
            size_t idx = (size_t)m * ldc + n;
            if (ATOMIC) atomicAdd(&C[idx], v);
            else C[idx] = v;
        }
    }
}

// ----------------------------------------------------------------------------
// LayerNorm over last dim (=1024), one row per 256-thread block. fp32.
// ----------------------------------------------------------------------------
template<bool RES>
__global__ __launch_bounds__(256)
void ln_k(const float* __restrict__ x, const float* __restrict__ res,
          const float* __restrict__ g, const float* __restrict__ b,
          float* __restrict__ outp)
{
    int row = blockIdx.x;
    int t = threadIdx.x;
    float4 v = reinterpret_cast<const float4*>(x + (size_t)row * 1024)[t];
    if (RES) {
        float4 r2 = reinterpret_cast<const float4*>(res + (size_t)row * 1024)[t];
        v.x += r2.x; v.y += r2.y; v.z += r2.z; v.w += r2.w;
    }
    float s  = v.x + v.y + v.z + v.w;
    float ss = v.x * v.x + v.y * v.y + v.z * v.z + v.w * v.w;
#pragma unroll
    for (int off = 32; off > 0; off >>= 1) {
        s  += __shfl_down(s, off, 64);
        ss += __shfl_down(ss, off, 64);
    }
    __shared__ float red[2][4];
    __shared__ float mv[2];
    int wid = t >> 6;
    if ((t & 63) == 0) { red[0][wid] = s; red[1][wid] = ss; }
    __syncthreads();
    if (t == 0) {
        float S  = red[0][0] + red[0][1] + red[0][2] + red[0][3];
        float SS = red[1][0] + red[1][1] + red[1][2] + red[1][3];
        float mean = S * (1.f / 1024.f);
        float var  = SS * (1.f / 1024.f) - mean * mean;
        mv[0] = mean; mv[1] = rsqrtf(var + 1e-5f);
    }
    __syncthreads();
    float mean = mv[0], rstd = mv[1];
    float4 gg = reinterpret_cast<const float4*>(g)[t];
    float4 bb = reinterpret_cast<const float4*>(b)[t];
    float4 ov;
    ov.x = (v.x - mean) * rstd * gg.x + bb.x;
    ov.y = (v.y - mean) * rstd * gg.y + bb.y;
    ov.z = (v.z - mean) * rstd * gg.z + bb.z;
    ov.w = (v.w - mean) * rstd * gg.w + bb.w;
    reinterpret_cast<float4*>(outp + (size_t)row * 1024)[t] = ov;
}

// ----------------------------------------------------------------------------
// MFMA flash attention partials. grid 512 = (b,h,qsp,split2); block 256 (4 waves).
// Wave w: 16 q-rows (qsp*64 + w*16 ..). KBLK=64 per iter, 1024 k per split.
// S^T = mfma(A=K rows, B=Q rows): D col=q (lane&15), row=k ((l>>4)*4+r +16mt).
// O^T = mfma(A=Vt rows d, B=P rows q): D col=q, row=d.
// ----------------------------------------------------------------------------
__global__ __launch_bounds__(256)
void attn_part_mfma(const float* __restrict__ qh, const float* __restrict__ kh,
                    const float* __restrict__ vh, float* __restrict__ pacc,
                    float* __restrict__ pml)
{
    const int bx = blockIdx.x;
    const int split = bx & 1;
    const int qsp = (bx >> 1) & 3;
    const int h = (bx >> 3) & 15;
    const int b = bx >> 7;
    const int tid = threadIdx.x;
    const int l = tid & 63, w = tid >> 6;
    const int g = l >> 4, q4 = l & 15;

    __shared__ alignas(16) unsigned short Ks[64][72];
    __shared__ alignas(16) unsigned short Vt[64][72];
    __shared__ alignas(16) unsigned short Ps[4][64][16];

    // Q fragments (B-operand): lane q4 -> q-row, octet g*8 + 32*dc
    s16x8 qf[2];
    {
        const int qrow = b * 256 + qsp * 64 + w * 16 + q4;
        const float* qp = qh + (size_t)qrow * 1024 + h * 64 + g * 8;
#pragma unroll
        for (int dc = 0; dc < 2; ++dc) {
            float4 a0 = *reinterpret_cast<const float4*>(qp + dc * 32);
            float4 a1 = *reinterpret_cast<const float4*>(qp + dc * 32 + 4);
            s16x8 v;
            v[0] = (short)f2bf(a0.x); v[1] = (short)f2bf(a0.y);
            v[2] = (short)f2bf(a0.z); v[3] = (short)f2bf(a0.w);
            v[4] = (short)f2bf(a1.x); v[5] = (short)f2bf(a1.y);
            v[6] = (short)f2bf(a1.z); v[7] = (short)f2bf(a1.w);
            qf[dc] = v;
        }
    }

    f32x4 oacc[4];
#pragma unroll
    for (int mi = 0; mi < 4; ++mi) oacc[mi] = (f32x4){0.f, 0.f, 0.f, 0.f};
    float m_run = -1e30f, l_run = 0.f;

    const float* khb = kh + ((size_t)b * 2048 + split * 1024) * 1024 + h * 64;
    const float* vhb = vh + ((size_t)b * 2048 + split * 1024) * 1024 + h * 64;

    const int krow = tid >> 2, dcol = (tid & 3) << 4;

    for (int kt = 0; kt < 1024; kt += 64) {
        __syncthreads();
        // ---- stage K (row-major bf16) and V (transposed bf16) ----
        {
            const float4* ks4 = reinterpret_cast<const float4*>(khb + (size_t)(kt + krow) * 1024 + dcol);
            float4 k0 = ks4[0], k1 = ks4[1], k2 = ks4[2], k3 = ks4[3];
            s16x8 v0, v1;
            v0[0] = (short)f2bf(k0.x); v0[1] = (short)f2bf(k0.y);
            v0[2] = (short)f2bf(k0.z); v0[3] = (short)f2bf(k0.w);
            v0[4] = (short)f2bf(k1.x); v0[5] = (short)f2bf(k1.y);
            v0[6] = (short)f2bf(k1.z); v0[7] = (short)f2bf(k1.w);
            v1[0] = (short)f2bf(k2.x); v1[1] = (short)f2bf(k2.y);
            v1[2] = (short)f2bf(k2.z); v1[3] = (short)f2bf(k2.w);
            v1[4] = (short)f2bf(k3.x); v1[5] = (short)f2bf(k3.y);
            v1[6] = (short)f2bf(k3.z); v1[7] = (short)f2bf(k3.w);
            *reinterpret_cast<s16x8*>(&Ks[krow][dcol]) = v0;
            *reinterpret_cast<s16x8*>(&Ks[krow][dcol + 8]) = v1;

            const float4* vs4 = reinterpret_cast<const float4*>(vhb + (size_t)(kt + krow) * 1024 + dcol);
            float4 w0 = vs4[0], w1 = vs4[1], w2 = vs4[2], w3 = vs4[3];
            unsigned short vv[16];
            vv[0] = f2bf(w0.x); vv[1] = f2bf(w0.y); vv[2] = f2bf(w0.z); vv[3] = f2bf(w0.w);
            vv[4] = f2bf(w1.x); vv[5] = f2bf(w1.y); vv[6] = f2bf(w1.z); vv[7] = f2bf(w1.w);
            vv[8] = f2bf(w2.x); vv[9] = f2bf(w2.y); vv[10] = f2bf(w2.z); vv[11] = f2bf(w2.w);
            vv[12] = f2bf(w3.x); vv[13] = f2bf(w3.y); vv[14] = f2bf(w3.z); vv[15] = f2bf(w3.w);
#pragma unroll
            for (int ii = 0; ii < 16; ++ii) Vt[dcol + ii][krow] = vv[ii];
        }
        __syncthreads();

        // ---- S^T = K · Q^T ----
        f32x4 sacc[4];
#pragma unroll
        for (int mt = 0; mt < 4; ++mt) sacc[mt] = (f32x4){0.f, 0.f, 0.f, 0.f};
#pragma unroll
        for (int dc = 0; dc < 2; ++dc) {
#pragma unroll
            for (int mt = 0; mt < 4; ++mt) {
                s16x8 ka = *reinterpret_cast<const s16x8*>(&Ks[mt * 16 + q4][g * 8 + dc * 32]);
                sacc[mt] = __builtin_amdgcn_mfma_f32_16x16x32_bf16(ka, qf[dc], sacc[mt], 0, 0, 0);
            }
        }

        // ---- online softmax (lane holds 16 k-values for q=q4) ----
        float p[16];
        float pmax = -1e30f;
#pragma unroll
        for (int mt = 0; mt < 4; ++mt)
#pragma unroll
            for (int r = 0; r < 4; ++r)
                pmax = fmaxf(pmax, sacc[mt][r] * 0.125f);
        pmax = fmaxf(pmax, __shfl_xor(pmax, 16));
        pmax = fmaxf(pmax, __shfl_xor(pmax, 32));
        float m_new = fmaxf(m_run, pmax);
        float sc_o = __expf(m_run - m_new);
        float lpart = 0.f;
#pragma unroll
        for (int mt = 0; mt < 4; ++mt)
#pragma unroll
            for (int r = 0; r < 4; ++r) {
                float pv = __expf(sacc[mt][r] * 0.125f - m_new);
                p[mt * 4 + r] = pv;
                lpart += pv;
            }
        lpart += __shfl_xor(lpart, 16);
        lpart += __shfl_xor(lpart, 32);
        l_run = l_run * sc_o + lpart;
        m_run = m_new;
#pragma unroll
        for (int mi = 0; mi < 4; ++mi)
#pragma unroll
            for (int r = 0; r < 4; ++r)
                oacc[mi][r] *= sc_o;

        // ---- P -> per-wave LDS [k][q] ----
#pragma unroll
        for (int mt = 0; mt < 4; ++mt)
#pragma unroll
            for (int r = 0; r < 4; ++r)
                Ps[w][mt * 16 + g * 4 + r][q4] = f2bf(p[mt * 4 + r]);

        // ---- O^T += Vt · P^T ----
#pragma unroll
        for (int kc = 0; kc < 2; ++kc) {
            s16x8 pb;
#pragma unroll
            for (int j = 0; j < 8; ++j)
                pb[j] = (short)Ps[w][kc * 32 + g * 8 + j][q4];
#pragma unroll
            for (int mi = 0; mi < 4; ++mi) {
                s16x8 va = *reinterpret_cast<const s16x8*>(&Vt[mi * 16 + q4][g * 8 + kc * 32]);
                oacc[mi] = __builtin_amdgcn_mfma_f32_16x16x32_bf16(va, pb, oacc[mi], 0, 0, 0);
            }
        }
    }

    // ---- epilogue: unnormalized partials ----
    const int rowg = (b * 16 + h) * 256 + qsp * 64 + w * 16 + q4;
    float* pa = pacc + ((size_t)split * 16384 + rowg) * 64;
#pragma unroll
    for (int mi = 0; mi < 4; ++mi)
        *reinterpret_cast<f32x4*>(pa + mi * 16 + g * 4) = oacc[mi];
    if (g == 0) {
        pml[((size_t)split * 16384 + rowg) * 2 + 0] = m_run;
        pml[((size_t)split * 16384 + rowg) * 2 + 1] = l_run;
    }
}

// combine 2 partials per q-row -> o
__global__ __launch_bounds__(64)
void attn_comb_k(const float* __restrict__ pacc, const float* __restrict__ pml,
                 float* __restrict__ o)
{
    int row = blockIdx.x * 64 + threadIdx.x;   // 0..16383
    float M = -1e30f;
#pragma unroll
    for (int s = 0; s < 2; ++s)
        M = fmaxf(M, pml[((size_t)s * 16384 + row) * 2]);
    float L = 0.f;
    float out[64] = {};
#pragma unroll
    for (int s = 0; s < 2; ++s) {
        float ms = pml[((size_t)s * 16384 + row) * 2 + 0];
        float ls = pml[((size_t)s * 16384 + row) * 2 + 1];
        float wgt = __expf(ms - M);
        L += wgt * ls;
        const float4* ap = reinterpret_cast<const float4*>(pacc + ((size_t)s * 16384 + row) * 64);
#pragma unroll
        for (int d4 = 0; d4 < 16; ++d4) {
            float4 a = ap[d4];
            out[d4 * 4 + 0] += wgt * a.x; out[d4 * 4 + 1] += wgt * a.y;
            out[d4 * 4 + 2] += wgt * a.z; out[d4 * 4 + 3] += wgt * a.w;
        }
    }
    float inv = 1.f / L;
    int t = row & 63, qt = (row >> 6) & 3, h = (row >> 8) & 15, b = row >> 12;
    float* op = o + (size_t)(b * 256 + qt * 64 + t) * 1024 + h * 64;
#pragma unroll
    for (int d4 = 0; d4 < 16; ++d4) {
        float4 v;
        v.x = out[d4 * 4 + 0] * inv; v.y = out[d4 * 4 + 1] * inv;
        v.z = out[d4 * 4 + 2] * inv; v.w = out[d4 * 4 + 3] * inv;
        *reinterpret_cast<float4*>(op + d4 * 4) = v;
    }
}

// hq[r,:] = qln[r%256,:] + oproj[r,:]
__global__ void add_bcast_k(const float* __restrict__ q, const float* __restrict__ o,
                            float* __restrict__ hq)
{
    int i = blockIdx.x * 256 + threadIdx.x;
    int r = i >> 8, c = i & 255;
    float4 qv = reinterpret_cast<const float4*>(q)[(r & 255) * 256 + c];
    float4 ov = reinterpret_cast<const float4*>(o)[i];
    float4 s; s.x = qv.x + ov.x; s.y = qv.y + ov.y; s.z = qv.z + ov.z; s.w = qv.w + ov.w;
    reinterpret_cast<float4*>(hq)[i] = s;
}

// causal depthwise conv (K=4) + bias + silu
__global__ void conv_k(const float* __restrict__ xz, const float* __restrict__ cw,
                       const float* __restrict__ cb, float* __restrict__ xc)
{
    int i = blockIdx.x * 256 + threadIdx.x;
    int r = i >> 11, c = i & 2047;
    int t = r & 255;
    float a = cb[c];
#pragma unroll
    for (int k = 0; k < 4; ++k) {
        int tt = t - 3 + k;
        if (tt >= 0) a += xz[(size_t)(r - 3 + k) * 4096 + c] * cw[c * 4 + k];
    }
    xc[i] = a / (1.f + expf(-a));
}

// ----------------------------------------------------------------------------
// mamba scan, 2-pass segmented: block = 16 (b,c) pairs x 4 time-segments of 64.
// grid 512 x 64. Pass1: segs 0..2 compute (E = prod e, U = local scan end).
// Combine in LDS -> h_start per segment. Pass2: rescan 64 steps emitting y.
// ----------------------------------------------------------------------------
__global__ __launch_bounds__(64)
void scan_k(const float* __restrict__ delta, const float* __restrict__ dbl,
            const float* __restrict__ xc, const float* __restrict__ Alog,
            float* __restrict__ ys)
{
    const int t = threadIdx.x;
    const int pi = t & 15, seg = t >> 4;
    const int pr = blockIdx.x * 16 + pi;
    const int c = pr & 2047, b = pr >> 11;

    float A[16];
#pragma unroll
    for (int n = 0; n < 16; ++n) A[n] = -expf(Alog[c * 16 + n]);

    __shared__ float HE[3][16][17];
    __shared__ float HU[3][16][17];

    if (seg < 3) {
        float h[16], E[16];
#pragma unroll
        for (int n = 0; n < 16; ++n) { h[n] = 0.f; E[n] = 1.f; }
        for (int s = 0; s < 64; ++s) {
            int r = b * 256 + seg * 64 + s;
            float dt = delta[(size_t)r * 2048 + c];
            float xv = xc[(size_t)r * 2048 + c];
            const float* row = dbl + (size_t)r * 96;
            float dx = dt * xv;
#pragma unroll
            for (int n = 0; n < 16; ++n) {
                float e = __expf(dt * A[n]);
                h[n] = e * h[n] + dx * row[64 + n];
                E[n] *= e;
            }
        }
#pragma unroll
        for (int n = 0; n < 16; ++n) { HE[seg][pi][n] = E[n]; HU[seg][pi][n] = h[n]; }
    }
    __syncthreads();

    float hs[16];
#pragma unroll
    for (int n = 0; n < 16; ++n) hs[n] = 0.f;
    for (int s2 = 0; s2 < seg; ++s2) {
#pragma unroll
        for (int n = 0; n < 16; ++n)
            hs[n] = HE[s2][pi][n] * hs[n] + HU[s2][pi][n];
    }

    for (int s = 0; s < 64; ++s) {
        int r = b * 256 + seg * 64 + s;
        float dt = delta[(size_t)r * 2048 + c];
        float xv = xc[(size_t)r * 2048 + c];
        const float* row = dbl + (size_t)r * 96;
        float dx = dt * xv;
        float y = 0.f;
#pragma unroll
        for (int n = 0; n < 16; ++n) {
            float e = __expf(dt * A[n]);
            hs[n] = e * hs[n] + dx * row[64 + n];
            y += hs[n] * row[80 + n];
        }
        ys[(size_t)r * 2048 + c] = y;
    }
}

// g = (ys + D*xc) * silu(z)
__global__ void gate_k(const float* __restrict__ ys, const float* __restrict__ xc,
                       const float* __restrict__ xz, const float* __restrict__ Dp,
                       float* __restrict__ g)
{
    int i = blockIdx.x * 256 + threadIdx.x;
    int r = i >> 9, c4 = i & 511;
    float4 y = reinterpret_cast<const float4*>(ys)[i];
    float4 x = reinterpret_cast<const float4*>(xc)[i];
    float4 z = reinterpret_cast<const float4*>(xz)[r * 1024 + 512 + c4];
    float4 d = reinterpret_cast<const float4*>(Dp)[c4];
    float4 o;
    o.x = (y.x + d.x * x.x) * (z.x / (1.f + expf(-z.x)));
    o.y = (y.y + d.y * x.y) * (z.y / (1.f + expf(-z.y)));
    o.z = (y.z + d.z * x.z) * (z.z / (1.f + expf(-z.z)));
    o.w = (y.w + d.w * x.w) * (z.w / (1.f + expf(-z.w)));
    reinterpret_cast<float4*>(g)[i] = o;
}

__global__ void fill_ones_f32(float* p, int n)
{
    int i = blockIdx.x * 256 + threadIdx.x;
    if (i < n) p[i] = 1.0f;
}

__global__ void fill_zero_f32(float* p, int n)
{
    int i = blockIdx.x * 256 + threadIdx.x;
    if (i < n) p[i] = 0.0f;
}

extern "C" void kernel_launch(void* const* d_in, const int* in_sizes, int n_in,
                              void* d_out, int out_size, void* d_ws, size_t ws_size,
                              hipStream_t stream)
{
    const float* x      = (const float*)d_in[0];
    const float* W_in   = (const float*)d_in[2];
    const float* b_in   = (const float*)d_in[3];
    const float* latents= (const float*)d_in[4];
    const float* lnq_g  = (const float*)d_in[5];
    const float* lnq_b  = (const float*)d_in[6];
    const float* lnkv_g = (const float*)d_in[7];
    const float* lnkv_b = (const float*)d_in[8];
    const float* W_qkv  = (const float*)d_in[9];
    const float* b_qkv  = (const float*)d_in[10];
    const float* W_o    = (const float*)d_in[11];
    const float* b_o    = (const float*)d_in[12];
    const float* W1     = (const float*)d_in[13];
    const float* b1     = (const float*)d_in[14];
    const float* W2     = (const float*)d_in[15];
    const float* b2     = (const float*)d_in[16];
    const float* lnf_g  = (const float*)d_in[17];
    const float* lnf_b  = (const float*)d_in[18];
    const float* mb_ln_g= (const float*)d_in[19];
    const float* mb_ln_b= (const float*)d_in[20];
    const float* mb_Win = (const float*)d_in[21];
    const float* mb_cw  = (const float*)d_in[22];
    const float* mb_cb  = (const float*)d_in[23];
    const float* mb_xp  = (const float*)d_in[24];
    const float* mb_dtW = (const float*)d_in[25];
    const float* mb_dtb = (const float*)d_in[26];
    const float* mb_Alog= (const float*)d_in[27];
    const float* mb_D   = (const float*)d_in[28];
    const float* mb_Wout= (const float*)d_in[29];
    const float* enc_g  = (const float*)d_in[30];
    const float* enc_b  = (const float*)d_in[31];
    const float* out_g  = (const float*)d_in[32];
    const float* out_b  = (const float*)d_in[33];

    float* W = (float*)d_ws;
    // persistent region
    float* kvh  = W + 0;          // 8192x1024: h -> LN in place -> kv; later attn pacc
    float* kh   = W + 8388608;    // 8192x1024
    float* vh   = W + 16777216;   // 8192x1024
    float* qln  = W + 25165824;   // 256x1024
    float* qh   = W + 25427968;   // 256x1024
    float* o_   = W + 25690112;   // 1024x1024
    float* op   = W + 26738688;   // 1024x1024 (pml during attn)
    float* hq   = W + 27787264;   // 1024x1024
    // overlay region (kvh/kh/vh dead by FFN/mamba time)
    float* u_   = W + 0;          // 1024x1024
    float* xz   = W + 1048576;    // 1024x4096
    float* xc   = W + 5242880;    // 1024x2048
    float* dbl  = W + 7340032;    // 1024x96
    float* dly  = W + 7471104;    // 1024x2048
    float* ysb  = W + 9568256;    // 1024x2048
    float* gb   = W + 11665408;   // 1024x2048
    float* ff1  = W + 13762560;   // 1024x2048
    float* tmp  = W + 15859712;   // 1024x1024
    // attn partials
    float* pacc = kvh;            // 2*16384*64 = 2097152 floats
    float* pml  = op;             // 2*16384*2  = 65536 floats

    dim3 blk(256);

    // 1. h = x @ W_in^T + b_in            [8192,1024,512]
    gemm_mfma<0,false,true><<<dim3(8,64),blk,0,stream>>>(x, W_in, b_in, kvh, 8192,1024,512, 512,512,1024);
    // 2. kv = LN(h) in place
    ln_k<false><<<8192,256,0,stream>>>(kvh, nullptr, lnkv_g, lnkv_b, kvh);
    // 3. qln = LN(latents)
    ln_k<false><<<256,256,0,stream>>>(latents, nullptr, lnq_g, lnq_b, qln);
    // 4. qh = qln @ Wq^T + bq             [256,1024,1024]
    gemm_mfma<0,false,true><<<dim3(8,2),blk,0,stream>>>(qln, W_qkv, b_qkv, qh, 256,1024,1024, 1024,1024,1024);
    // 5. kh = kv @ Wk^T + bk              [8192,1024,1024]
    gemm_mfma<0,false,true><<<dim3(8,64),blk,0,stream>>>(kvh, W_qkv+1048576, b_qkv+1024, kh, 8192,1024,1024, 1024,1024,1024);
    // 6. vh = kv @ Wv^T + bv
    gemm_mfma<0,false,true><<<dim3(8,64),blk,0,stream>>>(kvh, W_qkv+2097152, b_qkv+2048, vh, 8192,1024,1024, 1024,1024,1024);
    // 7. attention (MFMA, 2-way KV split + combine)
    attn_part_mfma<<<512,256,0,stream>>>(qh, kh, vh, pacc, pml);
    attn_comb_k<<<256,64,0,stream>>>(pacc, pml, o_);
    // 8. o proj                           [1024,1024,1024]
    gemm_mfma<0,false,true><<<dim3(8,8),blk,0,stream>>>(o_, W_o, b_o, op, 1024,1024,1024, 1024,1024,1024);
    // 9. hq = q + op
    add_bcast_k<<<1024,256,0,stream>>>(qln, op, hq);
    // 10. ff1 = gelu(hq @ W1^T + b1)      [1024,2048,1024]
    gemm_mfma<1,false,true><<<dim3(16,8),blk,0,stream>>>(hq, W1, b1, ff1, 1024,2048,1024, 1024,1024,2048);
    // 11. ff2                             [1024,1024,2048]
    gemm_mfma<0,false,true><<<dim3(8,8),blk,0,stream>>>(ff1, W2, b2, tmp, 1024,1024,2048, 2048,2048,1024);
    // 12. hq = LN(hq + ff2)
    ln_k<true><<<1024,256,0,stream>>>(hq, tmp, lnf_g, lnf_b, hq);
    // 13. mamba blocks
    for (int i = 0; i < 4; ++i) {
        ln_k<false><<<1024,256,0,stream>>>(hq, nullptr, mb_ln_g + i*1024, mb_ln_b + i*1024, u_);
        gemm_mfma<0,false,false><<<dim3(32,8),blk,0,stream>>>(u_, mb_Win + (size_t)i*4194304, nullptr, xz, 1024,4096,1024, 1024,1024,4096);
        conv_k<<<8192,256,0,stream>>>(xz, mb_cw + i*8192, mb_cb + i*2048, xc);
        fill_zero_f32<<<384,256,0,stream>>>(dbl, 98304);
        gemm_bt<0,false,true><<<dim3(2,16,8),blk,0,stream>>>(xc, mb_xp + i*196608, nullptr, dbl, 1024,96,2048, 2048,2048,96, 256);
        gemm_bt<2,true,false><<<dim3(32,16,1),blk,0,stream>>>(dbl, mb_dtW + i*131072, mb_dtb + i*2048, dly, 1024,2048,64, 96,64,2048, 64);
        scan_k<<<512,64,0,stream>>>(dly, dbl, xc, mb_Alog + i*32768, ysb);
        gate_k<<<2048,256,0,stream>>>(ysb, xc, xz, mb_D + i*2048, gb);
        gemm_mfma<0,true,false><<<dim3(8,8),blk,0,stream>>>(gb, mb_Wout + (size_t)i*2097152, nullptr, hq, 1024,1024,2048, 2048,2048,1024);
    }
    // 14. enc LN
    ln_k<false><<<1024,256,0,stream>>>(hq, nullptr, enc_g, enc_b, tmp);
    // 15. out LN -> fp32 d_out
    ln_k<false><<<1024,256,0,stream>>>(tmp, nullptr, out_g, out_b, (float*)d_out);
    // 16. comp_mask = ones
    fill_ones_f32<<<4,256,0,stream>>>((float*)d_out + 1048576, 1024);
}

// Round 6
// 1548.739 us; speedup vs baseline: 3.1809x; 1.2272x over previous
//
#include <hip/hip_runtime.h>
#include <hip/hip_bf16.h>
#include <math.h>

typedef __attribute__((ext_vector_type(8))) short s16x8;
typedef __attribute__((ext_vector_type(4))) float f32x4;

static __device__ __forceinline__ unsigned short f2bf(float f) {
    unsigned u = __builtin_bit_cast(unsigned, f);
    u += 0x7fffu + ((u >> 16) & 1u);   // RNE
    return (unsigned short)(u >> 16);
}

static __device__ __forceinline__ void gload16(const void* g, void* l) {
    __builtin_amdgcn_global_load_lds(
        (const __attribute__((address_space(1))) unsigned int*)g,
        (__attribute__((address_space(3))) unsigned int*)l, 16, 0, 0);
}

// ----------------------------------------------------------------------------
// bf16 MFMA GEMM (m97 structure): C[M,N] = act(A[M,K] * B[N,K]^T + bias)(+C)
// A,B bf16. 128x128 tile, BK=32, 4 waves 2x2, global_load_lds staging.
// OUT: 0 fp32 C, 1 bf16 C. ACT: 0 none, 1 gelu. M,N mult of 128, K mult of 32.
// ----------------------------------------------------------------------------
template<int ACT, bool ACC, bool BIAS, int OUT>
__global__ __launch_bounds__(256)
void gemm_bf16(const unsigned short* __restrict__ A, const unsigned short* __restrict__ B,
               const float* __restrict__ bias, float* __restrict__ Cf,
               unsigned short* __restrict__ Cb,
               int M, int N, int K, int lda, int ldb, int ldc)
{
    __shared__ alignas(16) unsigned short As[128][32];
    __shared__ alignas(16) unsigned short Bs[128][32];

    const int tid = threadIdx.x;
    const int m0 = blockIdx.y * 128;
    const int n0 = blockIdx.x * 128;
    const int l  = tid & 63;
    const int w  = tid >> 6;
    const int wr = w >> 1, wc = w & 1;
    const int fr = l & 15;
    const int fk = (l >> 4) * 8;
    const int srow = l >> 2;           // 0..15 within chunk
    const int skel = (l & 3) * 8;      // k element offset 0,8,16,24

    f32x4 acc[4][4];
#pragma unroll
    for (int i = 0; i < 4; ++i)
#pragma unroll
        for (int j = 0; j < 4; ++j) acc[i][j] = (f32x4){0.f, 0.f, 0.f, 0.f};

    for (int k0 = 0; k0 < K; k0 += 32) {
        // async global->LDS DMA: per wave 2 chunks of A + 2 of B (1KB each)
#pragma unroll
        for (int c = 0; c < 2; ++c) {
            const int r0 = w * 32 + c * 16;
            gload16(A + (size_t)(m0 + r0 + srow) * lda + k0 + skel, &As[r0][0]);
            gload16(B + (size_t)(n0 + r0 + srow) * ldb + k0 + skel, &Bs[r0][0]);
        }
        __syncthreads();

        s16x8 af[4], bfg[4];
#pragma unroll
        for (int mi = 0; mi < 4; ++mi)
            af[mi] = *reinterpret_cast<const s16x8*>(&As[wr * 64 + mi * 16 + fr][fk]);
#pragma unroll
        for (int ni = 0; ni < 4; ++ni)
            bfg[ni] = *reinterpret_cast<const s16x8*>(&Bs[wc * 64 + ni * 16 + fr][fk]);
#pragma unroll
        for (int mi = 0; mi < 4; ++mi)
#pragma unroll
            for (int ni = 0; ni < 4; ++ni)
                acc[mi][ni] = __builtin_amdgcn_mfma_f32_16x16x32_bf16(
                    af[mi], bfg[ni], acc[mi][ni], 0, 0, 0);
        __syncthreads();
    }

#pragma unroll
    for (int mi = 0; mi < 4; ++mi) {
#pragma unroll
        for (int ni = 0; ni < 4; ++ni) {
            const int col = n0 + wc * 64 + ni * 16 + fr;
            float bs = BIAS ? bias[col] : 0.f;
            f32x4 v = acc[mi][ni];
#pragma unroll
            for (int r = 0; r < 4; ++r) {
                const int row = m0 + wr * 64 + mi * 16 + (l >> 4) * 4 + r;
                float val = v[r] + bs;
                if (ACT == 1) val = 0.5f * val * (1.0f + erff(val * 0.70710678118654752440f));
                size_t idx = (size_t)row * ldc + col;
                if (OUT == 0) {
                    if (ACC) val += Cf[idx];
                    Cf[idx] = val;
                } else {
                    Cb[idx] = f2bf(val);
                }
            }
        }
    }
}

// ----------------------------------------------------------------------------
// fp32 GEMM (small/sensitive): C = act(A*B^T + bias); optional K-split atomic.
// ----------------------------------------------------------------------------
template<int ACT, bool BIAS, bool ATOMIC>
__global__ __launch_bounds__(256)
void gemm_bt(const float* __restrict__ A, const float* __restrict__ B,
             const float* __restrict__ bias, float* __restrict__ C,
             int M, int N, int K, int lda, int ldb, int ldc, int ksplit)
{
    __shared__ alignas(16) float As[16][68];
    __shared__ alignas(16) float Bs[16][68];
    const int tid = threadIdx.x;
    const int m0 = blockIdx.y * 64;
    const int n0 = blockIdx.x * 64;
    const int ty = tid >> 4, tx = tid & 15;
    const int lrow = tid >> 2;
    const int lk   = (tid & 3) << 2;

    float acc[4][4] = {};
    const int kbeg = blockIdx.z * ksplit;
    const int kend = kbeg + ksplit;

    for (int k0 = kbeg; k0 < kend; k0 += 16) {
        {
            int gr = m0 + lrow;
            float4 v; v.x = v.y = v.z = v.w = 0.f;
            if (gr < M) v = *reinterpret_cast<const float4*>(A + (size_t)gr * lda + k0 + lk);
            As[lk + 0][lrow] = v.x; As[lk + 1][lrow] = v.y;
            As[lk + 2][lrow] = v.z; As[lk + 3][lrow] = v.w;
        }
        {
            int gr = n0 + lrow;
            float4 v; v.x = v.y = v.z = v.w = 0.f;
            if (gr < N) v = *reinterpret_cast<const float4*>(B + (size_t)gr * ldb + k0 + lk);
            Bs[lk + 0][lrow] = v.x; Bs[lk + 1][lrow] = v.y;
            Bs[lk + 2][lrow] = v.z; Bs[lk + 3][lrow] = v.w;
        }
        __syncthreads();
#pragma unroll
        for (int k = 0; k < 16; ++k) {
            float4 a = *reinterpret_cast<const float4*>(&As[k][ty << 2]);
            float4 b = *reinterpret_cast<const float4*>(&Bs[k][tx << 2]);
            acc[0][0] += a.x * b.x; acc[0][1] += a.x * b.y; acc[0][2] += a.x * b.z; acc[0][3] += a.x * b.w;
            acc[1][0] += a.y * b.x; acc[1][1] += a.y * b.y; acc[1][2] += a.y * b.z; acc[1][3] += a.y * b.w;
            acc[2][0] += a.z * b.x; acc[2][1] += a.z * b.y; acc[2][2] += a.z * b.z; acc[2][3] += a.z * b.w;
            acc[3][0] += a.w * b.x; acc[3][1] += a.w * b.y; acc[3][2] += a.w * b.z; acc[3][3] += a.w * b.w;
        }
        __syncthreads();
    }

#pragma unroll
    for (int i = 0; i < 4; ++i) {
        int m = m0 + (ty << 2) + i;
        if (m >= M) continue;
#pragma unroll
        for (int j = 0; j < 4; ++j) {
            int n = n0 + (tx << 2) + j;
            if (n >= N) continue;
            float v = acc[i][j];
            if (BIAS && blockIdx.z == 0) v += bias[n];
            if (ACT == 2) v = fmaxf(v, 0.f) + log1pf(expf(-fabsf(v)));
            size_t idx = (size_t)m * ldc + n;
            if (ATOMIC) atomicAdd(&C[idx], v);
            else C[idx] = v;
        }
    }
}

// ----------------------------------------------------------------------------
// LayerNorm (last dim 1024), one row per block. OUT: 0 fp32, 1 bf16, 2 both.
// ----------------------------------------------------------------------------
template<bool RES, int OUT>
__global__ __launch_bounds__(256)
void ln_k(const float* __restrict__ x, const float* __restrict__ res,
          const float* __restrict__ g, const float* __restrict__ b,
          float* __restrict__ outf, unsigned short* __restrict__ outb)
{
    int row = blockIdx.x;
    int t = threadIdx.x;
    float4 v = reinterpret_cast<const float4*>(x + (size_t)row * 1024)[t];
    if (RES) {
        float4 r2 = reinterpret_cast<const float4*>(res + (size_t)row * 1024)[t];
        v.x += r2.x; v.y += r2.y; v.z += r2.z; v.w += r2.w;
    }
    float s  = v.x + v.y + v.z + v.w;
    float ss = v.x * v.x + v.y * v.y + v.z * v.z + v.w * v.w;
#pragma unroll
    for (int off = 32; off > 0; off >>= 1) {
        s  += __shfl_down(s, off, 64);
        ss += __shfl_down(ss, off, 64);
    }
    __shared__ float red[2][4];
    __shared__ float mv[2];
    int wid = t >> 6;
    if ((t & 63) == 0) { red[0][wid] = s; red[1][wid] = ss; }
    __syncthreads();
    if (t == 0) {
        float S  = red[0][0] + red[0][1] + red[0][2] + red[0][3];
        float SS = red[1][0] + red[1][1] + red[1][2] + red[1][3];
        float mean = S * (1.f / 1024.f);
        float var  = SS * (1.f / 1024.f) - mean * mean;
        mv[0] = mean; mv[1] = rsqrtf(var + 1e-5f);
    }
    __syncthreads();
    float mean = mv[0], rstd = mv[1];
    float4 gg = reinterpret_cast<const float4*>(g)[t];
    float4 bb = reinterpret_cast<const float4*>(b)[t];
    float y0 = (v.x - mean) * rstd * gg.x + bb.x;
    float y1 = (v.y - mean) * rstd * gg.y + bb.y;
    float y2 = (v.z - mean) * rstd * gg.z + bb.z;
    float y3 = (v.w - mean) * rstd * gg.w + bb.w;
    if (OUT == 0 || OUT == 2) {
        float4 ov; ov.x = y0; ov.y = y1; ov.z = y2; ov.w = y3;
        reinterpret_cast<float4*>(outf + (size_t)row * 1024)[t] = ov;
    }
    if (OUT == 1 || OUT == 2) {
        unsigned long long p = (unsigned long long)f2bf(y0)
                             | ((unsigned long long)f2bf(y1) << 16)
                             | ((unsigned long long)f2bf(y2) << 32)
                             | ((unsigned long long)f2bf(y3) << 48);
        *reinterpret_cast<unsigned long long*>(outb + (size_t)row * 1024 + t * 4) = p;
    }
}

// ----------------------------------------------------------------------------
// MFMA flash attention partials, bf16 inputs. grid 512=(b,h,qsp,split2), blk 256.
// q batch-shared (256 rows). Same S^T/O^T scheme as verified in round 5.
// ----------------------------------------------------------------------------
__global__ __launch_bounds__(256)
void attn_part_mfma(const unsigned short* __restrict__ qh,
                    const unsigned short* __restrict__ kh,
                    const unsigned short* __restrict__ vh,
                    float* __restrict__ pacc, float* __restrict__ pml)
{
    const int bx = blockIdx.x;
    const int split = bx & 1;
    const int qsp = (bx >> 1) & 3;
    const int h = (bx >> 3) & 15;
    const int b = bx >> 7;
    const int tid = threadIdx.x;
    const int l = tid & 63, w = tid >> 6;
    const int g = l >> 4, q4 = l & 15;

    __shared__ alignas(16) unsigned short Ks[64][72];
    __shared__ alignas(16) unsigned short Vt[64][72];
    __shared__ alignas(16) unsigned short Ps[4][64][16];

    s16x8 qf[2];
    {
        const int qrow = qsp * 64 + w * 16 + q4;   // q shared across batch
        const unsigned short* qp = qh + (size_t)qrow * 1024 + h * 64 + g * 8;
        qf[0] = *reinterpret_cast<const s16x8*>(qp);
        qf[1] = *reinterpret_cast<const s16x8*>(qp + 32);
    }

    f32x4 oacc[4];
#pragma unroll
    for (int mi = 0; mi < 4; ++mi) oacc[mi] = (f32x4){0.f, 0.f, 0.f, 0.f};
    float m_run = -1e30f, l_run = 0.f;

    const unsigned short* khb = kh + ((size_t)b * 2048 + split * 1024) * 1024 + h * 64;
    const unsigned short* vhb = vh + ((size_t)b * 2048 + split * 1024) * 1024 + h * 64;

    const int krow = tid >> 2, dcol = (tid & 3) << 4;

    for (int kt = 0; kt < 1024; kt += 64) {
        __syncthreads();
        {
            const unsigned short* ksrc = khb + (size_t)(kt + krow) * 1024 + dcol;
            s16x8 k0 = *reinterpret_cast<const s16x8*>(ksrc);
            s16x8 k1 = *reinterpret_cast<const s16x8*>(ksrc + 8);
            *reinterpret_cast<s16x8*>(&Ks[krow][dcol]) = k0;
            *reinterpret_cast<s16x8*>(&Ks[krow][dcol + 8]) = k1;
            const unsigned short* vsrc = vhb + (size_t)(kt + krow) * 1024 + dcol;
            s16x8 v0 = *reinterpret_cast<const s16x8*>(vsrc);
            s16x8 v1 = *reinterpret_cast<const s16x8*>(vsrc + 8);
#pragma unroll
            for (int ii = 0; ii < 8; ++ii) {
                Vt[dcol + ii][krow] = (unsigned short)v0[ii];
                Vt[dcol + 8 + ii][krow] = (unsigned short)v1[ii];
            }
        }
        __syncthreads();

        f32x4 sacc[4];
#pragma unroll
        for (int mt = 0; mt < 4; ++mt) sacc[mt] = (f32x4){0.f, 0.f, 0.f, 0.f};
#pragma unroll
        for (int dc = 0; dc < 2; ++dc) {
#pragma unroll
            for (int mt = 0; mt < 4; ++mt) {
                s16x8 ka = *reinterpret_cast<const s16x8*>(&Ks[mt * 16 + q4][g * 8 + dc * 32]);
                sacc[mt] = __builtin_amdgcn_mfma_f32_16x16x32_bf16(ka, qf[dc], sacc[mt], 0, 0, 0);
            }
        }

        float p[16];
        float pmax = -1e30f;
#pragma unroll
        for (int mt = 0; mt < 4; ++mt)
#pragma unroll
            for (int r = 0; r < 4; ++r)
                pmax = fmaxf(pmax, sacc[mt][r] * 0.125f);
        pmax = fmaxf(pmax, __shfl_xor(pmax, 16));
        pmax = fmaxf(pmax, __shfl_xor(pmax, 32));
        float m_new = fmaxf(m_run, pmax);
        float sc_o = __expf(m_run - m_new);
        float lpart = 0.f;
#pragma unroll
        for (int mt = 0; mt < 4; ++mt)
#pragma unroll
            for (int r = 0; r < 4; ++r) {
                float pv = __expf(sacc[mt][r] * 0.125f - m_new);
                p[mt * 4 + r] = pv;
                lpart += pv;
            }
        lpart += __shfl_xor(lpart, 16);
        lpart += __shfl_xor(lpart, 32);
        l_run = l_run * sc_o + lpart;
        m_run = m_new;
#pragma unroll
        for (int mi = 0; mi < 4; ++mi)
#pragma unroll
            for (int r = 0; r < 4; ++r)
                oacc[mi][r] *= sc_o;

#pragma unroll
        for (int mt = 0; mt < 4; ++mt)
#pragma unroll
            for (int r = 0; r < 4; ++r)
                Ps[w][mt * 16 + g * 4 + r][q4] = f2bf(p[mt * 4 + r]);

#pragma unroll
        for (int kc = 0; kc < 2; ++kc) {
            s16x8 pb;
#pragma unroll
            for (int j = 0; j < 8; ++j)
                pb[j] = (short)Ps[w][kc * 32 + g * 8 + j][q4];
#pragma unroll
            for (int mi = 0; mi < 4; ++mi) {
                s16x8 va = *reinterpret_cast<const s16x8*>(&Vt[mi * 16 + q4][g * 8 + kc * 32]);
                oacc[mi] = __builtin_amdgcn_mfma_f32_16x16x32_bf16(va, pb, oacc[mi], 0, 0, 0);
            }
        }
    }

    const int rowg = (b * 16 + h) * 256 + qsp * 64 + w * 16 + q4;
    float* pa = pacc + ((size_t)split * 16384 + rowg) * 64;
#pragma unroll
    for (int mi = 0; mi < 4; ++mi)
        *reinterpret_cast<f32x4*>(pa + mi * 16 + g * 4) = oacc[mi];
    if (g == 0) {
        pml[((size_t)split * 16384 + rowg) * 2 + 0] = m_run;
        pml[((size_t)split * 16384 + rowg) * 2 + 1] = l_run;
    }
}

// combine 2 partials per q-row -> bf16 o
__global__ __launch_bounds__(64)
void attn_comb_k(const float* __restrict__ pacc, const float* __restrict__ pml,
                 unsigned short* __restrict__ o)
{
    int row = blockIdx.x * 64 + threadIdx.x;   // 0..16383
    float M = -1e30f;
#pragma unroll
    for (int s = 0; s < 2; ++s)
        M = fmaxf(M, pml[((size_t)s * 16384 + row) * 2]);
    float L = 0.f;
    float out[64] = {};
#pragma unroll
    for (int s = 0; s < 2; ++s) {
        float ms = pml[((size_t)s * 16384 + row) * 2 + 0];
        float ls = pml[((size_t)s * 16384 + row) * 2 + 1];
        float wgt = __expf(ms - M);
        L += wgt * ls;
        const float4* ap = reinterpret_cast<const float4*>(pacc + ((size_t)s * 16384 + row) * 64);
#pragma unroll
        for (int d4 = 0; d4 < 16; ++d4) {
            float4 a = ap[d4];
            out[d4 * 4 + 0] += wgt * a.x; out[d4 * 4 + 1] += wgt * a.y;
            out[d4 * 4 + 2] += wgt * a.z; out[d4 * 4 + 3] += wgt * a.w;
        }
    }
    float inv = 1.f / L;
    int t = row & 63, qt = (row >> 6) & 3, h = (row >> 8) & 15, b = row >> 12;
    unsigned short* op = o + (size_t)(b * 256 + qt * 64 + t) * 1024 + h * 64;
#pragma unroll
    for (int d8 = 0; d8 < 8; ++d8) {
        s16x8 v;
#pragma unroll
        for (int j = 0; j < 8; ++j) v[j] = (short)f2bf(out[d8 * 8 + j] * inv);
        *reinterpret_cast<s16x8*>(op + d8 * 8) = v;
    }
}

// hq = qln[r%256] + op; writes fp32 + bf16
__global__ void add_bcast_k(const float* __restrict__ q, const float* __restrict__ o,
                            float* __restrict__ hq, unsigned short* __restrict__ hqb)
{
    int i = blockIdx.x * 256 + threadIdx.x;
    int r = i >> 8, c = i & 255;
    float4 qv = reinterpret_cast<const float4*>(q)[(r & 255) * 256 + c];
    float4 ov = reinterpret_cast<const float4*>(o)[i];
    float4 s; s.x = qv.x + ov.x; s.y = qv.y + ov.y; s.z = qv.z + ov.z; s.w = qv.w + ov.w;
    reinterpret_cast<float4*>(hq)[i] = s;
    unsigned long long p = (unsigned long long)f2bf(s.x)
                         | ((unsigned long long)f2bf(s.y) << 16)
                         | ((unsigned long long)f2bf(s.z) << 32)
                         | ((unsigned long long)f2bf(s.w) << 48);
    *reinterpret_cast<unsigned long long*>(hqb + (size_t)r * 1024 + c * 4) = p;
}

// causal depthwise conv (K=4) + bias + silu
__global__ void conv_k(const float* __restrict__ xz, const float* __restrict__ cw,
                       const float* __restrict__ cb, float* __restrict__ xc)
{
    int i = blockIdx.x * 256 + threadIdx.x;
    int r = i >> 11, c = i & 2047;
    int t = r & 255;
    float a = cb[c];
#pragma unroll
    for (int k = 0; k < 4; ++k) {
        int tt = t - 3 + k;
        if (tt >= 0) a += xz[(size_t)(r - 3 + k) * 4096 + c] * cw[c * 4 + k];
    }
    xc[i] = a / (1.f + expf(-a));
}

// mamba scan, 2-pass segmented (verified round 5)
__global__ __launch_bounds__(64)
void scan_k(const float* __restrict__ delta, const float* __restrict__ dbl,
            const float* __restrict__ xc, const float* __restrict__ Alog,
            float* __restrict__ ys)
{
    const int t = threadIdx.x;
    const int pi = t & 15, seg = t >> 4;
    const int pr = blockIdx.x * 16 + pi;
    const int c = pr & 2047, b = pr >> 11;

    float A[16];
#pragma unroll
    for (int n = 0; n < 16; ++n) A[n] = -expf(Alog[c * 16 + n]);

    __shared__ float HE[3][16][17];
    __shared__ float HU[3][16][17];

    if (seg < 3) {
        float h[16], E[16];
#pragma unroll
        for (int n = 0; n < 16; ++n) { h[n] = 0.f; E[n] = 1.f; }
        for (int s = 0; s < 64; ++s) {
            int r = b * 256 + seg * 64 + s;
            float dt = delta[(size_t)r * 2048 + c];
            float xv = xc[(size_t)r * 2048 + c];
            const float* row = dbl + (size_t)r * 96;
            float dx = dt * xv;
#pragma unroll
            for (int n = 0; n < 16; ++n) {
                float e = __expf(dt * A[n]);
                h[n] = e * h[n] + dx * row[64 + n];
                E[n] *= e;
            }
        }
#pragma unroll
        for (int n = 0; n < 16; ++n) { HE[seg][pi][n] = E[n]; HU[seg][pi][n] = h[n]; }
    }
    __syncthreads();

    float hs[16];
#pragma unroll
    for (int n = 0; n < 16; ++n) hs[n] = 0.f;
    for (int s2 = 0; s2 < seg; ++s2) {
#pragma unroll
        for (int n = 0; n < 16; ++n)
            hs[n] = HE[s2][pi][n] * hs[n] + HU[s2][pi][n];
    }

    for (int s = 0; s < 64; ++s) {
        int r = b * 256 + seg * 64 + s;
        float dt = delta[(size_t)r * 2048 + c];
        float xv = xc[(size_t)r * 2048 + c];
        const float* row = dbl + (size_t)r * 96;
        float dx = dt * xv;
        float y = 0.f;
#pragma unroll
        for (int n = 0; n < 16; ++n) {
            float e = __expf(dt * A[n]);
            hs[n] = e * hs[n] + dx * row[64 + n];
            y += hs[n] * row[80 + n];
        }
        ys[(size_t)r * 2048 + c] = y;
    }
}

// g = (ys + D*xc) * silu(z) -> bf16, 8 elems/thread
__global__ void gate_k(const float* __restrict__ ys, const float* __restrict__ xc,
                       const float* __restrict__ xz, const float* __restrict__ Dp,
                       unsigned short* __restrict__ g)
{
    int i = blockIdx.x * 256 + threadIdx.x;   // 0..262143
    int r = i >> 8, c8 = (i & 255) * 8;
    const float4* yp = reinterpret_cast<const float4*>(ys + (size_t)r * 2048 + c8);
    const float4* xp = reinterpret_cast<const float4*>(xc + (size_t)r * 2048 + c8);
    const float4* zp = reinterpret_cast<const float4*>(xz + (size_t)r * 4096 + 2048 + c8);
    const float4* dp = reinterpret_cast<const float4*>(Dp + c8);
    s16x8 o;
#pragma unroll
    for (int hx = 0; hx < 2; ++hx) {
        float4 y = yp[hx], x = xp[hx], z = zp[hx], d = dp[hx];
        float v0 = (y.x + d.x * x.x) * (z.x / (1.f + expf(-z.x)));
        float v1 = (y.y + d.y * x.y) * (z.y / (1.f + expf(-z.y)));
        float v2 = (y.z + d.z * x.z) * (z.z / (1.f + expf(-z.z)));
        float v3 = (y.w + d.w * x.w) * (z.w / (1.f + expf(-z.w)));
        o[hx * 4 + 0] = (short)f2bf(v0); o[hx * 4 + 1] = (short)f2bf(v1);
        o[hx * 4 + 2] = (short)f2bf(v2); o[hx * 4 + 3] = (short)f2bf(v3);
    }
    *reinterpret_cast<s16x8*>(g + (size_t)r * 2048 + c8) = o;
}

// fp32 -> bf16 bulk convert, 8 elems/thread, n = grid*2048 exactly
__global__ __launch_bounds__(256)
void cvt_bf16_k(const float* __restrict__ in, unsigned short* __restrict__ out)
{
    size_t i = ((size_t)blockIdx.x * 256 + threadIdx.x) * 8;
    float4 a = *reinterpret_cast<const float4*>(in + i);
    float4 b = *reinterpret_cast<const float4*>(in + i + 4);
    s16x8 v;
    v[0] = (short)f2bf(a.x); v[1] = (short)f2bf(a.y);
    v[2] = (short)f2bf(a.z); v[3] = (short)f2bf(a.w);
    v[4] = (short)f2bf(b.x); v[5] = (short)f2bf(b.y);
    v[6] = (short)f2bf(b.z); v[7] = (short)f2bf(b.w);
    *reinterpret_cast<s16x8*>(out + i) = v;
}

__global__ void fill_ones_f32(float* p, int n)
{
    int i = blockIdx.x * 256 + threadIdx.x;
    if (i < n) p[i] = 1.0f;
}

__global__ void fill_zero_f32(float* p, int n)
{
    int i = blockIdx.x * 256 + threadIdx.x;
    if (i < n) p[i] = 0.0f;
}

extern "C" void kernel_launch(void* const* d_in, const int* in_sizes, int n_in,
                              void* d_out, int out_size, void* d_ws, size_t ws_size,
                              hipStream_t stream)
{
    const float* x      = (const float*)d_in[0];
    const float* W_in   = (const float*)d_in[2];
    const float* b_in   = (const float*)d_in[3];
    const float* latents= (const float*)d_in[4];
    const float* lnq_g  = (const float*)d_in[5];
    const float* lnq_b  = (const float*)d_in[6];
    const float* lnkv_g = (const float*)d_in[7];
    const float* lnkv_b = (const float*)d_in[8];
    const float* W_qkv  = (const float*)d_in[9];
    const float* b_qkv  = (const float*)d_in[10];
    const float* W_o    = (const float*)d_in[11];
    const float* b_o    = (const float*)d_in[12];
    const float* W1     = (const float*)d_in[13];
    const float* b1     = (const float*)d_in[14];
    const float* W2     = (const float*)d_in[15];
    const float* b2     = (const float*)d_in[16];
    const float* lnf_g  = (const float*)d_in[17];
    const float* lnf_b  = (const float*)d_in[18];
    const float* mb_ln_g= (const float*)d_in[19];
    const float* mb_ln_b= (const float*)d_in[20];
    const float* mb_Win = (const float*)d_in[21];
    const float* mb_cw  = (const float*)d_in[22];
    const float* mb_cb  = (const float*)d_in[23];
    const float* mb_xp  = (const float*)d_in[24];
    const float* mb_dtW = (const float*)d_in[25];
    const float* mb_dtb = (const float*)d_in[26];
    const float* mb_Alog= (const float*)d_in[27];
    const float* mb_D   = (const float*)d_in[28];
    const float* mb_Wout= (const float*)d_in[29];
    const float* enc_g  = (const float*)d_in[30];
    const float* enc_b  = (const float*)d_in[31];
    const float* out_g  = (const float*)d_in[32];
    const float* out_b  = (const float*)d_in[33];

    float* W = (float*)d_ws;
    typedef unsigned short us;
    // fp32 persistents (high-water 28835840 fl = 115.3 MB, proven)
    float* kvh  = W + 0;           // h fp32 [8192x1024]; later pacc
    float* qln  = W + 25165824;    // 256x1024
    float* op   = W + 26738688;    // 1024x1024 (pml during attn)
    float* hq   = W + 27787264;    // 1024x1024
    // bf16 pool over old kh/vh region: fl [8388608, 25165824)
    us* P       = (us*)(W + 8388608);
    us* kv_bf   = P + 0;           // 8192x1024
    us* kh_bf   = P + 8388608;     // 8192x1024
    us* vh_bf   = P + 16777216;    // 8192x1024
    us* qh_bf   = P + 25165824;    // 256x1024
    us* Wqkv_bf = P + 25427968;    // 3145728
    us* Win_bf  = P + 28573696;    // 524288
    us* xbf     = P + 29097984;    // 4194304 (ends 33292288 <= 33554432)
    // post-attention scratch in dead kvh region
    float* pacc = kvh;             // 2*16384*64 = 2097152 fl
    float* pml  = op;              // 65536 fl
    us* Wo_bf   = (us*)(W + 2097152);   // 1048576
    us* W1_bf   = (us*)(W + 0);         // 2097152
    us* W2_bf   = (us*)(W + 1048576);   // 2097152
    us* ff1_bf  = (us*)(W + 3145728);   // 2097152
    us* hq_bf   = (us*)(W + 4194304);   // 1048576
    us* o_bf    = (us*)(W + 25690112);  // 1048576
    us* qln_bf  = (us*)(W + 26214400);  // 262144
    // mamba per-iter scratch
    us* u_bf    = (us*)(W + 0);         // 1048576
    us* Win_s   = (us*)(W + 524288);    // 4194304
    us* Wout_s  = (us*)(W + 2621440);   // 2097152
    float* xz   = W + 3670016;          // 1024x4096
    float* xc   = W + 7864320;          // 1024x2048
    float* dbl  = W + 9961472;          // 1024x96
    float* dly  = W + 10092544;         // 1024x2048
    float* ysb  = W + 12189696;         // 1024x2048
    us* gb_bf   = (us*)(W + 14286848);  // 2097152
    float* tmp  = W + 15859712;         // 1024x1024

    dim3 blk(256);

    // convert inputs/weights for phase 1
    cvt_bf16_k<<<2048,blk,0,stream>>>(x, xbf);
    cvt_bf16_k<<<256,blk,0,stream>>>(W_in, Win_bf);
    cvt_bf16_k<<<1536,blk,0,stream>>>(W_qkv, Wqkv_bf);
    // 1. h = x @ W_in^T + b_in
    gemm_bf16<0,false,true,0><<<dim3(8,64),blk,0,stream>>>(xbf, Win_bf, b_in, kvh, nullptr, 8192,1024,512, 512,512,1024);
    // 2. kv = LN(h) -> bf16
    ln_k<false,1><<<8192,blk,0,stream>>>(kvh, nullptr, lnkv_g, lnkv_b, nullptr, kv_bf);
    // 3. qln = LN(latents) -> fp32 + bf16
    ln_k<false,2><<<256,blk,0,stream>>>(latents, nullptr, lnq_g, lnq_b, qln, qln_bf);
    // 4-6. q/k/v projections -> bf16
    gemm_bf16<0,false,true,1><<<dim3(8,2),blk,0,stream>>>(qln_bf, Wqkv_bf, b_qkv, nullptr, qh_bf, 256,1024,1024, 1024,1024,1024);
    gemm_bf16<0,false,true,1><<<dim3(8,64),blk,0,stream>>>(kv_bf, Wqkv_bf+1048576, b_qkv+1024, nullptr, kh_bf, 8192,1024,1024, 1024,1024,1024);
    gemm_bf16<0,false,true,1><<<dim3(8,64),blk,0,stream>>>(kv_bf, Wqkv_bf+2097152, b_qkv+2048, nullptr, vh_bf, 8192,1024,1024, 1024,1024,1024);
    // 7. attention
    attn_part_mfma<<<512,blk,0,stream>>>(qh_bf, kh_bf, vh_bf, pacc, pml);
    cvt_bf16_k<<<512,blk,0,stream>>>(W_o, Wo_bf);
    attn_comb_k<<<256,64,0,stream>>>(pacc, pml, o_bf);
    // 8. o proj
    gemm_bf16<0,false,true,0><<<dim3(8,8),blk,0,stream>>>(o_bf, Wo_bf, b_o, op, nullptr, 1024,1024,1024, 1024,1024,1024);
    // 9. hq = q + op
    add_bcast_k<<<1024,blk,0,stream>>>(qln, op, hq, hq_bf);
    // 10-11. FFN
    cvt_bf16_k<<<1024,blk,0,stream>>>(W1, W1_bf);
    cvt_bf16_k<<<1024,blk,0,stream>>>(W2, W2_bf);
    gemm_bf16<1,false,true,1><<<dim3(16,8),blk,0,stream>>>(hq_bf, W1_bf, b1, nullptr, ff1_bf, 1024,2048,1024, 1024,1024,2048);
    gemm_bf16<0,false,true,0><<<dim3(8,8),blk,0,stream>>>(ff1_bf, W2_bf, b2, tmp, nullptr, 1024,1024,2048, 2048,2048,1024);
    // 12. hq = LN(hq + ff2)
    ln_k<true,0><<<1024,blk,0,stream>>>(hq, tmp, lnf_g, lnf_b, hq, nullptr);
    // 13. mamba blocks
    for (int i = 0; i < 4; ++i) {
        cvt_bf16_k<<<2048,blk,0,stream>>>(mb_Win + (size_t)i*4194304, Win_s);
        cvt_bf16_k<<<1024,blk,0,stream>>>(mb_Wout + (size_t)i*2097152, Wout_s);
        ln_k<false,1><<<1024,blk,0,stream>>>(hq, nullptr, mb_ln_g + i*1024, mb_ln_b + i*1024, nullptr, u_bf);
        gemm_bf16<0,false,false,0><<<dim3(32,8),blk,0,stream>>>(u_bf, Win_s, nullptr, xz, nullptr, 1024,4096,1024, 1024,1024,4096);
        conv_k<<<8192,blk,0,stream>>>(xz, mb_cw + i*8192, mb_cb + i*2048, xc);
        fill_zero_f32<<<384,blk,0,stream>>>(dbl, 98304);
        gemm_bt<0,false,true><<<dim3(2,16,8),blk,0,stream>>>(xc, mb_xp + i*196608, nullptr, dbl, 1024,96,2048, 2048,2048,96, 256);
        gemm_bt<2,true,false><<<dim3(32,16,1),blk,0,stream>>>(dbl, mb_dtW + i*131072, mb_dtb + i*2048, dly, 1024,2048,64, 96,64,2048, 64);
        scan_k<<<512,64,0,stream>>>(dly, dbl, xc, mb_Alog + i*32768, ysb);
        gate_k<<<1024,blk,0,stream>>>(ysb, xc, xz, mb_D + i*2048, gb_bf);
        gemm_bf16<0,true,false,0><<<dim3(8,8),blk,0,stream>>>(gb_bf, Wout_s, nullptr, hq, nullptr, 1024,1024,2048, 2048,2048,1024);
    }
    // 14-15. final LNs
    ln_k<false,0><<<1024,blk,0,stream>>>(hq, nullptr, enc_g, enc_b, tmp, nullptr);
    ln_k<false,0><<<1024,blk,0,stream>>>(tmp, nullptr, out_g, out_b, (float*)d_out, nullptr);
    // 16. comp_mask = ones
    fill_ones_f32<<<4,blk,0,stream>>>((float*)d_out + 1048576, 1024);
}

// Round 7
// 1050.067 us; speedup vs baseline: 4.6914x; 1.4749x over previous
//
#include <hip/hip_runtime.h>
#include <hip/hip_bf16.h>
#include <math.h>

typedef __attribute__((ext_vector_type(8))) short s16x8;
typedef __attribute__((ext_vector_type(4))) float f32x4;

static __device__ __forceinline__ unsigned short f2bf(float f) {
    unsigned u = __builtin_bit_cast(unsigned, f);
    u += 0x7fffu + ((u >> 16) & 1u);   // RNE
    return (unsigned short)(u >> 16);
}

static __device__ __forceinline__ void gload16(const void* g, void* l) {
    __builtin_amdgcn_global_load_lds(
        (const __attribute__((address_space(1))) unsigned int*)g,
        (__attribute__((address_space(3))) unsigned int*)l, 16, 0, 0);
}

// ----------------------------------------------------------------------------
// bf16 MFMA GEMM, 128x128 tile, BK=32, 4 waves 2x2 (proven round 6).
// ----------------------------------------------------------------------------
template<int ACT, bool ACC, bool BIAS, int OUT>
__global__ __launch_bounds__(256)
void gemm_bf16(const unsigned short* __restrict__ A, const unsigned short* __restrict__ B,
               const float* __restrict__ bias, float* __restrict__ Cf,
               unsigned short* __restrict__ Cb,
               int M, int N, int K, int lda, int ldb, int ldc)
{
    __shared__ alignas(16) unsigned short As[128][32];
    __shared__ alignas(16) unsigned short Bs[128][32];

    const int tid = threadIdx.x;
    const int m0 = blockIdx.y * 128;
    const int n0 = blockIdx.x * 128;
    const int l  = tid & 63;
    const int w  = tid >> 6;
    const int wr = w >> 1, wc = w & 1;
    const int fr = l & 15;
    const int fk = (l >> 4) * 8;
    const int srow = l >> 2;
    const int skel = (l & 3) * 8;

    f32x4 acc[4][4];
#pragma unroll
    for (int i = 0; i < 4; ++i)
#pragma unroll
        for (int j = 0; j < 4; ++j) acc[i][j] = (f32x4){0.f, 0.f, 0.f, 0.f};

    for (int k0 = 0; k0 < K; k0 += 32) {
#pragma unroll
        for (int c = 0; c < 2; ++c) {
            const int r0 = w * 32 + c * 16;
            gload16(A + (size_t)(m0 + r0 + srow) * lda + k0 + skel, &As[r0][0]);
            gload16(B + (size_t)(n0 + r0 + srow) * ldb + k0 + skel, &Bs[r0][0]);
        }
        __syncthreads();

        s16x8 af[4], bfg[4];
#pragma unroll
        for (int mi = 0; mi < 4; ++mi)
            af[mi] = *reinterpret_cast<const s16x8*>(&As[wr * 64 + mi * 16 + fr][fk]);
#pragma unroll
        for (int ni = 0; ni < 4; ++ni)
            bfg[ni] = *reinterpret_cast<const s16x8*>(&Bs[wc * 64 + ni * 16 + fr][fk]);
#pragma unroll
        for (int mi = 0; mi < 4; ++mi)
#pragma unroll
            for (int ni = 0; ni < 4; ++ni)
                acc[mi][ni] = __builtin_amdgcn_mfma_f32_16x16x32_bf16(
                    af[mi], bfg[ni], acc[mi][ni], 0, 0, 0);
        __syncthreads();
    }

#pragma unroll
    for (int mi = 0; mi < 4; ++mi) {
#pragma unroll
        for (int ni = 0; ni < 4; ++ni) {
            const int col = n0 + wc * 64 + ni * 16 + fr;
            float bs = BIAS ? bias[col] : 0.f;
            f32x4 v = acc[mi][ni];
#pragma unroll
            for (int r = 0; r < 4; ++r) {
                const int row = m0 + wr * 64 + mi * 16 + (l >> 4) * 4 + r;
                float val = v[r] + bs;
                if (ACT == 1) val = 0.5f * val * (1.0f + erff(val * 0.70710678118654752440f));
                size_t idx = (size_t)row * ldc + col;
                if (OUT == 0) {
                    if (ACC) val += Cf[idx];
                    Cf[idx] = val;
                } else {
                    Cb[idx] = f2bf(val);
                }
            }
        }
    }
}

// ----------------------------------------------------------------------------
// bf16 MFMA GEMM, 64x64 tile, BK=32, 4 waves 2x2 of 32x32 (CU-coverage variant
// for small-M GEMMs). Same LDS/fragment layout rules as the 128 tile.
// ----------------------------------------------------------------------------
template<int ACT, bool ACC, bool BIAS, int OUT>
__global__ __launch_bounds__(256)
void gemm_bf16_t64(const unsigned short* __restrict__ A, const unsigned short* __restrict__ B,
                   const float* __restrict__ bias, float* __restrict__ Cf,
                   unsigned short* __restrict__ Cb,
                   int M, int N, int K, int lda, int ldb, int ldc)
{
    __shared__ alignas(16) unsigned short As[64][32];
    __shared__ alignas(16) unsigned short Bs[64][32];

    const int tid = threadIdx.x;
    const int m0 = blockIdx.y * 64;
    const int n0 = blockIdx.x * 64;
    const int l  = tid & 63;
    const int w  = tid >> 6;
    const int wr = w >> 1, wc = w & 1;
    const int fr = l & 15;
    const int fk = (l >> 4) * 8;

    f32x4 acc[2][2];
#pragma unroll
    for (int i = 0; i < 2; ++i)
#pragma unroll
        for (int j = 0; j < 2; ++j) acc[i][j] = (f32x4){0.f, 0.f, 0.f, 0.f};

    for (int k0 = 0; k0 < K; k0 += 32) {
        // one issue: 256 threads x 16B = 4KB = whole 64x32 bf16 tile
        gload16(A + (size_t)(m0 + w * 16 + (l >> 2)) * lda + k0 + (l & 3) * 8, &As[w * 16][0]);
        gload16(B + (size_t)(n0 + w * 16 + (l >> 2)) * ldb + k0 + (l & 3) * 8, &Bs[w * 16][0]);
        __syncthreads();

        s16x8 af[2], bfg[2];
#pragma unroll
        for (int mi = 0; mi < 2; ++mi)
            af[mi] = *reinterpret_cast<const s16x8*>(&As[wr * 32 + mi * 16 + fr][fk]);
#pragma unroll
        for (int ni = 0; ni < 2; ++ni)
            bfg[ni] = *reinterpret_cast<const s16x8*>(&Bs[wc * 32 + ni * 16 + fr][fk]);
#pragma unroll
        for (int mi = 0; mi < 2; ++mi)
#pragma unroll
            for (int ni = 0; ni < 2; ++ni)
                acc[mi][ni] = __builtin_amdgcn_mfma_f32_16x16x32_bf16(
                    af[mi], bfg[ni], acc[mi][ni], 0, 0, 0);
        __syncthreads();
    }

#pragma unroll
    for (int mi = 0; mi < 2; ++mi) {
#pragma unroll
        for (int ni = 0; ni < 2; ++ni) {
            const int col = n0 + wc * 32 + ni * 16 + fr;
            float bs = BIAS ? bias[col] : 0.f;
            f32x4 v = acc[mi][ni];
#pragma unroll
            for (int r = 0; r < 4; ++r) {
                const int row = m0 + wr * 32 + mi * 16 + (l >> 4) * 4 + r;
                float val = v[r] + bs;
                if (ACT == 1) val = 0.5f * val * (1.0f + erff(val * 0.70710678118654752440f));
                size_t idx = (size_t)row * ldc + col;
                if (OUT == 0) {
                    if (ACC) val += Cf[idx];
                    Cf[idx] = val;
                } else {
                    Cb[idx] = f2bf(val);
                }
            }
        }
    }
}

// ----------------------------------------------------------------------------
// fp32 GEMM (small/sensitive): C = act(A*B^T + bias); optional K-split atomic.
// ----------------------------------------------------------------------------
template<int ACT, bool BIAS, bool ATOMIC>
__global__ __launch_bounds__(256)
void gemm_bt(const float* __restrict__ A, const float* __restrict__ B,
             const float* __restrict__ bias, float* __restrict__ C,
             int M, int N, int K, int lda, int ldb, int ldc, int ksplit)
{
    __shared__ alignas(16) float As[16][68];
    __shared__ alignas(16) float Bs[16][68];
    const int tid = threadIdx.x;
    const int m0 = blockIdx.y * 64;
    const int n0 = blockIdx.x * 64;
    const int ty = tid >> 4, tx = tid & 15;
    const int lrow = tid >> 2;
    const int lk   = (tid & 3) << 2;

    float acc[4][4] = {};
    const int kbeg = blockIdx.z * ksplit;
    const int kend = kbeg + ksplit;

    for (int k0 = kbeg; k0 < kend; k0 += 16) {
        {
            int gr = m0 + lrow;
            float4 v; v.x = v.y = v.z = v.w = 0.f;
            if (gr < M) v = *reinterpret_cast<const float4*>(A + (size_t)gr * lda + k0 + lk);
            As[lk + 0][lrow] = v.x; As[lk + 1][lrow] = v.y;
            As[lk + 2][lrow] = v.z; As[lk + 3][lrow] = v.w;
        }
        {
            int gr = n0 + lrow;
            float4 v; v.x = v.y = v.z = v.w = 0.f;
            if (gr < N) v = *reinterpret_cast<const float4*>(B + (size_t)gr * ldb + k0 + lk);
            Bs[lk + 0][lrow] = v.x; Bs[lk + 1][lrow] = v.y;
            Bs[lk + 2][lrow] = v.z; Bs[lk + 3][lrow] = v.w;
        }
        __syncthreads();
#pragma unroll
        for (int k = 0; k < 16; ++k) {
            float4 a = *reinterpret_cast<const float4*>(&As[k][ty << 2]);
            float4 b = *reinterpret_cast<const float4*>(&Bs[k][tx << 2]);
            acc[0][0] += a.x * b.x; acc[0][1] += a.x * b.y; acc[0][2] += a.x * b.z; acc[0][3] += a.x * b.w;
            acc[1][0] += a.y * b.x; acc[1][1] += a.y * b.y; acc[1][2] += a.y * b.z; acc[1][3] += a.y * b.w;
            acc[2][0] += a.z * b.x; acc[2][1] += a.z * b.y; acc[2][2] += a.z * b.z; acc[2][3] += a.z * b.w;
            acc[3][0] += a.w * b.x; acc[3][1] += a.w * b.y; acc[3][2] += a.w * b.z; acc[3][3] += a.w * b.w;
        }
        __syncthreads();
    }

#pragma unroll
    for (int i = 0; i < 4; ++i) {
        int m = m0 + (ty << 2) + i;
        if (m >= M) continue;
#pragma unroll
        for (int j = 0; j < 4; ++j) {
            int n = n0 + (tx << 2) + j;
            if (n >= N) continue;
            float v = acc[i][j];
            if (BIAS && blockIdx.z == 0) v += bias[n];
            if (ACT == 2) v = fmaxf(v, 0.f) + log1pf(expf(-fabsf(v)));
            size_t idx = (size_t)m * ldc + n;
            if (ATOMIC) atomicAdd(&C[idx], v);
            else C[idx] = v;
        }
    }
}

// ----------------------------------------------------------------------------
// LayerNorm (last dim 1024), one row per block. OUT: 0 fp32, 1 bf16, 2 both.
// ----------------------------------------------------------------------------
template<bool RES, int OUT>
__global__ __launch_bounds__(256)
void ln_k(const float* __restrict__ x, const float* __restrict__ res,
          const float* __restrict__ g, const float* __restrict__ b,
          float* __restrict__ outf, unsigned short* __restrict__ outb)
{
    int row = blockIdx.x;
    int t = threadIdx.x;
    float4 v = reinterpret_cast<const float4*>(x + (size_t)row * 1024)[t];
    if (RES) {
        float4 r2 = reinterpret_cast<const float4*>(res + (size_t)row * 1024)[t];
        v.x += r2.x; v.y += r2.y; v.z += r2.z; v.w += r2.w;
    }
    float s  = v.x + v.y + v.z + v.w;
    float ss = v.x * v.x + v.y * v.y + v.z * v.z + v.w * v.w;
#pragma unroll
    for (int off = 32; off > 0; off >>= 1) {
        s  += __shfl_down(s, off, 64);
        ss += __shfl_down(ss, off, 64);
    }
    __shared__ float red[2][4];
    __shared__ float mv[2];
    int wid = t >> 6;
    if ((t & 63) == 0) { red[0][wid] = s; red[1][wid] = ss; }
    __syncthreads();
    if (t == 0) {
        float S  = red[0][0] + red[0][1] + red[0][2] + red[0][3];
        float SS = red[1][0] + red[1][1] + red[1][2] + red[1][3];
        float mean = S * (1.f / 1024.f);
        float var  = SS * (1.f / 1024.f) - mean * mean;
        mv[0] = mean; mv[1] = rsqrtf(var + 1e-5f);
    }
    __syncthreads();
    float mean = mv[0], rstd = mv[1];
    float4 gg = reinterpret_cast<const float4*>(g)[t];
    float4 bb = reinterpret_cast<const float4*>(b)[t];
    float y0 = (v.x - mean) * rstd * gg.x + bb.x;
    float y1 = (v.y - mean) * rstd * gg.y + bb.y;
    float y2 = (v.z - mean) * rstd * gg.z + bb.z;
    float y3 = (v.w - mean) * rstd * gg.w + bb.w;
    if (OUT == 0 || OUT == 2) {
        float4 ov; ov.x = y0; ov.y = y1; ov.z = y2; ov.w = y3;
        reinterpret_cast<float4*>(outf + (size_t)row * 1024)[t] = ov;
    }
    if (OUT == 1 || OUT == 2) {
        unsigned long long p = (unsigned long long)f2bf(y0)
                             | ((unsigned long long)f2bf(y1) << 16)
                             | ((unsigned long long)f2bf(y2) << 32)
                             | ((unsigned long long)f2bf(y3) << 48);
        *reinterpret_cast<unsigned long long*>(outb + (size_t)row * 1024 + t * 4) = p;
    }
}

// ----------------------------------------------------------------------------
// MFMA flash attention partials (verified round 6).
// ----------------------------------------------------------------------------
__global__ __launch_bounds__(256)
void attn_part_mfma(const unsigned short* __restrict__ qh,
                    const unsigned short* __restrict__ kh,
                    const unsigned short* __restrict__ vh,
                    float* __restrict__ pacc, float* __restrict__ pml)
{
    const int bx = blockIdx.x;
    const int split = bx & 1;
    const int qsp = (bx >> 1) & 3;
    const int h = (bx >> 3) & 15;
    const int b = bx >> 7;
    const int tid = threadIdx.x;
    const int l = tid & 63, w = tid >> 6;
    const int g = l >> 4, q4 = l & 15;

    __shared__ alignas(16) unsigned short Ks[64][72];
    __shared__ alignas(16) unsigned short Vt[64][72];
    __shared__ alignas(16) unsigned short Ps[4][64][16];

    s16x8 qf[2];
    {
        const int qrow = qsp * 64 + w * 16 + q4;
        const unsigned short* qp = qh + (size_t)qrow * 1024 + h * 64 + g * 8;
        qf[0] = *reinterpret_cast<const s16x8*>(qp);
        qf[1] = *reinterpret_cast<const s16x8*>(qp + 32);
    }

    f32x4 oacc[4];
#pragma unroll
    for (int mi = 0; mi < 4; ++mi) oacc[mi] = (f32x4){0.f, 0.f, 0.f, 0.f};
    float m_run = -1e30f, l_run = 0.f;

    const unsigned short* khb = kh + ((size_t)b * 2048 + split * 1024) * 1024 + h * 64;
    const unsigned short* vhb = vh + ((size_t)b * 2048 + split * 1024) * 1024 + h * 64;

    const int krow = tid >> 2, dcol = (tid & 3) << 4;

    for (int kt = 0; kt < 1024; kt += 64) {
        __syncthreads();
        {
            const unsigned short* ksrc = khb + (size_t)(kt + krow) * 1024 + dcol;
            s16x8 k0 = *reinterpret_cast<const s16x8*>(ksrc);
            s16x8 k1 = *reinterpret_cast<const s16x8*>(ksrc + 8);
            *reinterpret_cast<s16x8*>(&Ks[krow][dcol]) = k0;
            *reinterpret_cast<s16x8*>(&Ks[krow][dcol + 8]) = k1;
            const unsigned short* vsrc = vhb + (size_t)(kt + krow) * 1024 + dcol;
            s16x8 v0 = *reinterpret_cast<const s16x8*>(vsrc);
            s16x8 v1 = *reinterpret_cast<const s16x8*>(vsrc + 8);
#pragma unroll
            for (int ii = 0; ii < 8; ++ii) {
                Vt[dcol + ii][krow] = (unsigned short)v0[ii];
                Vt[dcol + 8 + ii][krow] = (unsigned short)v1[ii];
            }
        }
        __syncthreads();

        f32x4 sacc[4];
#pragma unroll
        for (int mt = 0; mt < 4; ++mt) sacc[mt] = (f32x4){0.f, 0.f, 0.f, 0.f};
#pragma unroll
        for (int dc = 0; dc < 2; ++dc) {
#pragma unroll
            for (int mt = 0; mt < 4; ++mt) {
                s16x8 ka = *reinterpret_cast<const s16x8*>(&Ks[mt * 16 + q4][g * 8 + dc * 32]);
                sacc[mt] = __builtin_amdgcn_mfma_f32_16x16x32_bf16(ka, qf[dc], sacc[mt], 0, 0, 0);
            }
        }

        float p[16];
        float pmax = -1e30f;
#pragma unroll
        for (int mt = 0; mt < 4; ++mt)
#pragma unroll
            for (int r = 0; r < 4; ++r)
                pmax = fmaxf(pmax, sacc[mt][r] * 0.125f);
        pmax = fmaxf(pmax, __shfl_xor(pmax, 16));
        pmax = fmaxf(pmax, __shfl_xor(pmax, 32));
        float m_new = fmaxf(m_run, pmax);
        float sc_o = __expf(m_run - m_new);
        float lpart = 0.f;
#pragma unroll
        for (int mt = 0; mt < 4; ++mt)
#pragma unroll
            for (int r = 0; r < 4; ++r) {
                float pv = __expf(sacc[mt][r] * 0.125f - m_new);
                p[mt * 4 + r] = pv;
                lpart += pv;
            }
        lpart += __shfl_xor(lpart, 16);
        lpart += __shfl_xor(lpart, 32);
        l_run = l_run * sc_o + lpart;
        m_run = m_new;
#pragma unroll
        for (int mi = 0; mi < 4; ++mi)
#pragma unroll
            for (int r = 0; r < 4; ++r)
                oacc[mi][r] *= sc_o;

#pragma unroll
        for (int mt = 0; mt < 4; ++mt)
#pragma unroll
            for (int r = 0; r < 4; ++r)
                Ps[w][mt * 16 + g * 4 + r][q4] = f2bf(p[mt * 4 + r]);

#pragma unroll
        for (int kc = 0; kc < 2; ++kc) {
            s16x8 pb;
#pragma unroll
            for (int j = 0; j < 8; ++j)
                pb[j] = (short)Ps[w][kc * 32 + g * 8 + j][q4];
#pragma unroll
            for (int mi = 0; mi < 4; ++mi) {
                s16x8 va = *reinterpret_cast<const s16x8*>(&Vt[mi * 16 + q4][g * 8 + kc * 32]);
                oacc[mi] = __builtin_amdgcn_mfma_f32_16x16x32_bf16(va, pb, oacc[mi], 0, 0, 0);
            }
        }
    }

    const int rowg = (b * 16 + h) * 256 + qsp * 64 + w * 16 + q4;
    float* pa = pacc + ((size_t)split * 16384 + rowg) * 64;
#pragma unroll
    for (int mi = 0; mi < 4; ++mi)
        *reinterpret_cast<f32x4*>(pa + mi * 16 + g * 4) = oacc[mi];
    if (g == 0) {
        pml[((size_t)split * 16384 + rowg) * 2 + 0] = m_run;
        pml[((size_t)split * 16384 + rowg) * 2 + 1] = l_run;
    }
}

// combine 2 partials per q-row -> bf16 o
__global__ __launch_bounds__(64)
void attn_comb_k(const float* __restrict__ pacc, const float* __restrict__ pml,
                 unsigned short* __restrict__ o)
{
    int row = blockIdx.x * 64 + threadIdx.x;
    float M = -1e30f;
#pragma unroll
    for (int s = 0; s < 2; ++s)
        M = fmaxf(M, pml[((size_t)s * 16384 + row) * 2]);
    float L = 0.f;
    float out[64] = {};
#pragma unroll
    for (int s = 0; s < 2; ++s) {
        float ms = pml[((size_t)s * 16384 + row) * 2 + 0];
        float ls = pml[((size_t)s * 16384 + row) * 2 + 1];
        float wgt = __expf(ms - M);
        L += wgt * ls;
        const float4* ap = reinterpret_cast<const float4*>(pacc + ((size_t)s * 16384 + row) * 64);
#pragma unroll
        for (int d4 = 0; d4 < 16; ++d4) {
            float4 a = ap[d4];
            out[d4 * 4 + 0] += wgt * a.x; out[d4 * 4 + 1] += wgt * a.y;
            out[d4 * 4 + 2] += wgt * a.z; out[d4 * 4 + 3] += wgt * a.w;
        }
    }
    float inv = 1.f / L;
    int t = row & 63, qt = (row >> 6) & 3, h = (row >> 8) & 15, b = row >> 12;
    unsigned short* op = o + (size_t)(b * 256 + qt * 64 + t) * 1024 + h * 64;
#pragma unroll
    for (int d8 = 0; d8 < 8; ++d8) {
        s16x8 v;
#pragma unroll
        for (int j = 0; j < 8; ++j) v[j] = (short)f2bf(out[d8 * 8 + j] * inv);
        *reinterpret_cast<s16x8*>(op + d8 * 8) = v;
    }
}

// hq = qln[r%256] + op; writes fp32 + bf16
__global__ void add_bcast_k(const float* __restrict__ q, const float* __restrict__ o,
                            float* __restrict__ hq, unsigned short* __restrict__ hqb)
{
    int i = blockIdx.x * 256 + threadIdx.x;
    int r = i >> 8, c = i & 255;
    float4 qv = reinterpret_cast<const float4*>(q)[(r & 255) * 256 + c];
    float4 ov = reinterpret_cast<const float4*>(o)[i];
    float4 s; s.x = qv.x + ov.x; s.y = qv.y + ov.y; s.z = qv.z + ov.z; s.w = qv.w + ov.w;
    reinterpret_cast<float4*>(hq)[i] = s;
    unsigned long long p = (unsigned long long)f2bf(s.x)
                         | ((unsigned long long)f2bf(s.y) << 16)
                         | ((unsigned long long)f2bf(s.z) << 32)
                         | ((unsigned long long)f2bf(s.w) << 48);
    *reinterpret_cast<unsigned long long*>(hqb + (size_t)r * 1024 + c * 4) = p;
}

// causal depthwise conv (K=4) + bias + silu
__global__ void conv_k(const float* __restrict__ xz, const float* __restrict__ cw,
                       const float* __restrict__ cb, float* __restrict__ xc)
{
    int i = blockIdx.x * 256 + threadIdx.x;
    int r = i >> 11, c = i & 2047;
    int t = r & 255;
    float a = cb[c];
#pragma unroll
    for (int k = 0; k < 4; ++k) {
        int tt = t - 3 + k;
        if (tt >= 0) a += xz[(size_t)(r - 3 + k) * 4096 + c] * cw[c * 4 + k];
    }
    xc[i] = a / (1.f + expf(-a));
}

// ----------------------------------------------------------------------------
// mamba scan, 2-pass, 16 segments of 16 steps. Block = 16 pairs x 16 segs.
// grid 512 x 256 -> 8 waves/CU.
// ----------------------------------------------------------------------------
__global__ __launch_bounds__(256)
void scan_k(const float* __restrict__ delta, const float* __restrict__ dbl,
            const float* __restrict__ xc, const float* __restrict__ Alog,
            float* __restrict__ ys)
{
    const int t = threadIdx.x;
    const int pi = t & 15, seg = t >> 4;       // seg 0..15
    const int pr = blockIdx.x * 16 + pi;       // (b,c) pair
    const int c = pr & 2047, b = pr >> 11;

    float A[16];
#pragma unroll
    for (int n = 0; n < 16; ++n) A[n] = -expf(Alog[c * 16 + n]);

    __shared__ float HE[15][16][17];
    __shared__ float HU[15][16][17];

    if (seg < 15) {
        float h[16], E[16];
#pragma unroll
        for (int n = 0; n < 16; ++n) { h[n] = 0.f; E[n] = 1.f; }
        for (int s = 0; s < 16; ++s) {
            int r = b * 256 + seg * 16 + s;
            float dt = delta[(size_t)r * 2048 + c];
            float xv = xc[(size_t)r * 2048 + c];
            const float* row = dbl + (size_t)r * 96;
            float dx = dt * xv;
#pragma unroll
            for (int n = 0; n < 16; ++n) {
                float e = __expf(dt * A[n]);
                h[n] = e * h[n] + dx * row[64 + n];
                E[n] *= e;
            }
        }
#pragma unroll
        for (int n = 0; n < 16; ++n) { HE[seg][pi][n] = E[n]; HU[seg][pi][n] = h[n]; }
    }
    __syncthreads();

    float hs[16];
#pragma unroll
    for (int n = 0; n < 16; ++n) hs[n] = 0.f;
    for (int s2 = 0; s2 < seg; ++s2) {
#pragma unroll
        for (int n = 0; n < 16; ++n)
            hs[n] = HE[s2][pi][n] * hs[n] + HU[s2][pi][n];
    }

    for (int s = 0; s < 16; ++s) {
        int r = b * 256 + seg * 16 + s;
        float dt = delta[(size_t)r * 2048 + c];
        float xv = xc[(size_t)r * 2048 + c];
        const float* row = dbl + (size_t)r * 96;
        float dx = dt * xv;
        float y = 0.f;
#pragma unroll
        for (int n = 0; n < 16; ++n) {
            float e = __expf(dt * A[n]);
            hs[n] = e * hs[n] + dx * row[64 + n];
            y += hs[n] * row[80 + n];
        }
        ys[(size_t)r * 2048 + c] = y;
    }
}

// g = (ys + D*xc) * silu(z) -> bf16, 8 elems/thread
__global__ void gate_k(const float* __restrict__ ys, const float* __restrict__ xc,
                       const float* __restrict__ xz, const float* __restrict__ Dp,
                       unsigned short* __restrict__ g)
{
    int i = blockIdx.x * 256 + threadIdx.x;
    int r = i >> 8, c8 = (i & 255) * 8;
    const float4* yp = reinterpret_cast<const float4*>(ys + (size_t)r * 2048 + c8);
    const float4* xp = reinterpret_cast<const float4*>(xc + (size_t)r * 2048 + c8);
    const float4* zp = reinterpret_cast<const float4*>(xz + (size_t)r * 4096 + 2048 + c8);
    const float4* dp = reinterpret_cast<const float4*>(Dp + c8);
    s16x8 o;
#pragma unroll
    for (int hx = 0; hx < 2; ++hx) {
        float4 y = yp[hx], x = xp[hx], z = zp[hx], d = dp[hx];
        float v0 = (y.x + d.x * x.x) * (z.x / (1.f + expf(-z.x)));
        float v1 = (y.y + d.y * x.y) * (z.y / (1.f + expf(-z.y)));
        float v2 = (y.z + d.z * x.z) * (z.z / (1.f + expf(-z.z)));
        float v3 = (y.w + d.w * x.w) * (z.w / (1.f + expf(-z.w)));
        o[hx * 4 + 0] = (short)f2bf(v0); o[hx * 4 + 1] = (short)f2bf(v1);
        o[hx * 4 + 2] = (short)f2bf(v2); o[hx * 4 + 3] = (short)f2bf(v3);
    }
    *reinterpret_cast<s16x8*>(g + (size_t)r * 2048 + c8) = o;
}

// fp32 -> bf16 bulk convert, 8 elems/thread, n = grid*2048 exactly
__global__ __launch_bounds__(256)
void cvt_bf16_k(const float* __restrict__ in, unsigned short* __restrict__ out)
{
    size_t i = ((size_t)blockIdx.x * 256 + threadIdx.x) * 8;
    float4 a = *reinterpret_cast<const float4*>(in + i);
    float4 b = *reinterpret_cast<const float4*>(in + i + 4);
    s16x8 v;
    v[0] = (short)f2bf(a.x); v[1] = (short)f2bf(a.y);
    v[2] = (short)f2bf(a.z); v[3] = (short)f2bf(a.w);
    v[4] = (short)f2bf(b.x); v[5] = (short)f2bf(b.y);
    v[6] = (short)f2bf(b.z); v[7] = (short)f2bf(b.w);
    *reinterpret_cast<s16x8*>(out + i) = v;
}

__global__ void fill_ones_f32(float* p, int n)
{
    int i = blockIdx.x * 256 + threadIdx.x;
    if (i < n) p[i] = 1.0f;
}

__global__ void fill_zero_f32(float* p, int n)
{
    int i = blockIdx.x * 256 + threadIdx.x;
    if (i < n) p[i] = 0.0f;
}

extern "C" void kernel_launch(void* const* d_in, const int* in_sizes, int n_in,
                              void* d_out, int out_size, void* d_ws, size_t ws_size,
                              hipStream_t stream)
{
    const float* x      = (const float*)d_in[0];
    const float* W_in   = (const float*)d_in[2];
    const float* b_in   = (const float*)d_in[3];
    const float* latents= (const float*)d_in[4];
    const float* lnq_g  = (const float*)d_in[5];
    const float* lnq_b  = (const float*)d_in[6];
    const float* lnkv_g = (const float*)d_in[7];
    const float* lnkv_b = (const float*)d_in[8];
    const float* W_qkv  = (const float*)d_in[9];
    const float* b_qkv  = (const float*)d_in[10];
    const float* W_o    = (const float*)d_in[11];
    const float* b_o    = (const float*)d_in[12];
    const float* W1     = (const float*)d_in[13];
    const float* b1     = (const float*)d_in[14];
    const float* W2     = (const float*)d_in[15];
    const float* b2     = (const float*)d_in[16];
    const float* lnf_g  = (const float*)d_in[17];
    const float* lnf_b  = (const float*)d_in[18];
    const float* mb_ln_g= (const float*)d_in[19];
    const float* mb_ln_b= (const float*)d_in[20];
    const float* mb_Win = (const float*)d_in[21];
    const float* mb_cw  = (const float*)d_in[22];
    const float* mb_cb  = (const float*)d_in[23];
    const float* mb_xp  = (const float*)d_in[24];
    const float* mb_dtW = (const float*)d_in[25];
    const float* mb_dtb = (const float*)d_in[26];
    const float* mb_Alog= (const float*)d_in[27];
    const float* mb_D   = (const float*)d_in[28];
    const float* mb_Wout= (const float*)d_in[29];
    const float* enc_g  = (const float*)d_in[30];
    const float* enc_b  = (const float*)d_in[31];
    const float* out_g  = (const float*)d_in[32];
    const float* out_b  = (const float*)d_in[33];

    float* W = (float*)d_ws;
    typedef unsigned short us;
    // --- phase A (through attention), layout proven in round 6 ---
    float* kvh  = W + 0;           // h fp32 [8192x1024]; later pacc
    float* qln  = W + 25165824;    // 256x1024
    float* op   = W + 26738688;    // 1024x1024 (pml during attn)
    float* hq   = W + 27787264;    // 1024x1024 (persistent)
    us* P       = (us*)(W + 8388608);
    us* kv_bf   = P + 0;           // 8192x1024
    us* kh_bf   = P + 8388608;     // 8192x1024
    us* vh_bf   = P + 16777216;    // 8192x1024
    us* qh_bf   = P + 25165824;    // 256x1024
    us* Wqkv_bf = P + 25427968;    // 3145728
    us* Win_bf  = P + 28573696;    // 524288
    us* xbf     = P + 29097984;    // 4194304
    float* pacc = kvh;             // 2*16384*64 fl
    float* pml  = op;              // 65536 fl
    // --- phase A2 (o-proj / FFN) scratch in dead kvh region ---
    us* Wo_bf   = (us*)(W + 2097152);   // 1048576 (safe next to pacc)
    us* W1_bf   = (us*)(W + 0);         // 2097152
    us* W2_bf   = (us*)(W + 1048576);   // 2097152
    us* ff1_bf  = (us*)(W + 3145728);   // 2097152
    us* hq_bf   = (us*)(W + 4194304);   // 1048576
    us* o_bf    = (us*)(W + 25690112);  // 1048576
    us* qln_bf  = (us*)(W + 26214400);  // 262144
    // --- phase B (mamba): weights hoisted into dead kv/kh/vh region ---
    us* Win_all = (us*)(W + 8388608);   // 16777216 shorts (fl 8.39M..16.78M)
    us* Wout_all= (us*)(W + 16777216);  // 8388608 shorts (fl 16.78M..20.97M)
    us* u_bf    = (us*)(W + 0);         // 1048576 shorts (fl 0..0.52M)
    float* xz   = W + 524288;           // 4194304 fl (..4718592)
    float* xc   = W + 4718592;          // 2097152 fl (..6815744)
    float* dbl  = W + 6815744;          // 98304 fl
    float* dly  = W + 20971520;         // 2097152 fl (..23068672)
    float* ysb  = W + 23068672;         // 2097152 fl (..25165824)
    us* gb_bf   = (us*)(W + 25165824);  // 2097152 shorts (fl ..26214400)
    float* tmp  = W + 26214400;         // 1048576 fl (..27262976)

    dim3 blk(256);

    // convert inputs/weights for phase 1
    cvt_bf16_k<<<2048,blk,0,stream>>>(x, xbf);
    cvt_bf16_k<<<256,blk,0,stream>>>(W_in, Win_bf);
    cvt_bf16_k<<<1536,blk,0,stream>>>(W_qkv, Wqkv_bf);
    // 1. h = x @ W_in^T + b_in
    gemm_bf16<0,false,true,0><<<dim3(8,64),blk,0,stream>>>(xbf, Win_bf, b_in, kvh, nullptr, 8192,1024,512, 512,512,1024);
    // 2. kv = LN(h) -> bf16
    ln_k<false,1><<<8192,blk,0,stream>>>(kvh, nullptr, lnkv_g, lnkv_b, nullptr, kv_bf);
    // 3. qln = LN(latents) -> fp32 + bf16
    ln_k<false,2><<<256,blk,0,stream>>>(latents, nullptr, lnq_g, lnq_b, qln, qln_bf);
    // 4-6. q/k/v projections -> bf16
    gemm_bf16_t64<0,false,true,1><<<dim3(16,4),blk,0,stream>>>(qln_bf, Wqkv_bf, b_qkv, nullptr, qh_bf, 256,1024,1024, 1024,1024,1024);
    gemm_bf16<0,false,true,1><<<dim3(8,64),blk,0,stream>>>(kv_bf, Wqkv_bf+1048576, b_qkv+1024, nullptr, kh_bf, 8192,1024,1024, 1024,1024,1024);
    gemm_bf16<0,false,true,1><<<dim3(8,64),blk,0,stream>>>(kv_bf, Wqkv_bf+2097152, b_qkv+2048, nullptr, vh_bf, 8192,1024,1024, 1024,1024,1024);
    // 7. attention
    attn_part_mfma<<<512,blk,0,stream>>>(qh_bf, kh_bf, vh_bf, pacc, pml);
    cvt_bf16_k<<<512,blk,0,stream>>>(W_o, Wo_bf);
    attn_comb_k<<<256,64,0,stream>>>(pacc, pml, o_bf);
    // 8. o proj
    gemm_bf16_t64<0,false,true,0><<<dim3(16,16),blk,0,stream>>>(o_bf, Wo_bf, b_o, op, nullptr, 1024,1024,1024, 1024,1024,1024);
    // 9. hq = q + op
    add_bcast_k<<<1024,blk,0,stream>>>(qln, op, hq, hq_bf);
    // 10-11. FFN
    cvt_bf16_k<<<1024,blk,0,stream>>>(W1, W1_bf);
    cvt_bf16_k<<<1024,blk,0,stream>>>(W2, W2_bf);
    gemm_bf16_t64<1,false,true,1><<<dim3(32,16),blk,0,stream>>>(hq_bf, W1_bf, b1, nullptr, ff1_bf, 1024,2048,1024, 1024,1024,2048);
    gemm_bf16_t64<0,false,true,0><<<dim3(16,16),blk,0,stream>>>(ff1_bf, W2_bf, b2, tmp, nullptr, 1024,1024,2048, 2048,2048,1024);
    // 12. hq = LN(hq + ff2)
    ln_k<true,0><<<1024,blk,0,stream>>>(hq, tmp, lnf_g, lnf_b, hq, nullptr);
    // hoisted mamba weight conversion (kh/vh dead after attention)
    cvt_bf16_k<<<8192,blk,0,stream>>>(mb_Win, Win_all);
    cvt_bf16_k<<<4096,blk,0,stream>>>(mb_Wout, Wout_all);
    // 13. mamba blocks
    for (int i = 0; i < 4; ++i) {
        ln_k<false,1><<<1024,blk,0,stream>>>(hq, nullptr, mb_ln_g + i*1024, mb_ln_b + i*1024, nullptr, u_bf);
        gemm_bf16<0,false,false,0><<<dim3(32,8),blk,0,stream>>>(u_bf, Win_all + (size_t)i*4194304, nullptr, xz, nullptr, 1024,4096,1024, 1024,1024,4096);
        conv_k<<<8192,blk,0,stream>>>(xz, mb_cw + i*8192, mb_cb + i*2048, xc);
        fill_zero_f32<<<384,blk,0,stream>>>(dbl, 98304);
        gemm_bt<0,false,true><<<dim3(2,16,8),blk,0,stream>>>(xc, mb_xp + i*196608, nullptr, dbl, 1024,96,2048, 2048,2048,96, 256);
        gemm_bt<2,true,false><<<dim3(32,16,1),blk,0,stream>>>(dbl, mb_dtW + i*131072, mb_dtb + i*2048, dly, 1024,2048,64, 96,64,2048, 64);
        scan_k<<<512,blk,0,stream>>>(dly, dbl, xc, mb_Alog + i*32768, ysb);
        gate_k<<<1024,blk,0,stream>>>(ysb, xc, xz, mb_D + i*2048, gb_bf);
        gemm_bf16_t64<0,true,false,0><<<dim3(16,16),blk,0,stream>>>(gb_bf, Wout_all + (size_t)i*2097152, nullptr, hq, nullptr, 1024,1024,2048, 2048,2048,1024);
    }
    // 14-15. final LNs
    ln_k<false,0><<<1024,blk,0,stream>>>(hq, nullptr, enc_g, enc_b, tmp, nullptr);
    ln_k<false,0><<<1024,blk,0,stream>>>(tmp, nullptr, out_g, out_b, (float*)d_out, nullptr);
    // 16. comp_mask = ones
    fill_ones_f32<<<4,blk,0,stream>>>((float*)d_out + 1048576, 1024);
}

// Round 8
// 1014.542 us; speedup vs baseline: 4.8557x; 1.0350x over previous
//
#include <hip/hip_runtime.h>
#include <hip/hip_bf16.h>
#include <math.h>

typedef __attribute__((ext_vector_type(8))) short s16x8;
typedef __attribute__((ext_vector_type(4))) float f32x4;

static __device__ __forceinline__ unsigned short f2bf(float f) {
    unsigned u = __builtin_bit_cast(unsigned, f);
    u += 0x7fffu + ((u >> 16) & 1u);   // RNE
    return (unsigned short)(u >> 16);
}

static __device__ __forceinline__ void gload16(const void* g, void* l) {
    __builtin_amdgcn_global_load_lds(
        (const __attribute__((address_space(1))) unsigned int*)g,
        (__attribute__((address_space(3))) unsigned int*)l, 16, 0, 0);
}

// ----------------------------------------------------------------------------
// bf16 MFMA GEMM, 128x128 tile, BK=32, 4 waves 2x2 (proven round 6).
// ----------------------------------------------------------------------------
template<int ACT, bool ACC, bool BIAS, int OUT>
__global__ __launch_bounds__(256)
void gemm_bf16(const unsigned short* __restrict__ A, const unsigned short* __restrict__ B,
               const float* __restrict__ bias, float* __restrict__ Cf,
               unsigned short* __restrict__ Cb,
               int M, int N, int K, int lda, int ldb, int ldc)
{
    __shared__ alignas(16) unsigned short As[128][32];
    __shared__ alignas(16) unsigned short Bs[128][32];

    const int tid = threadIdx.x;
    const int m0 = blockIdx.y * 128;
    const int n0 = blockIdx.x * 128;
    const int l  = tid & 63;
    const int w  = tid >> 6;
    const int wr = w >> 1, wc = w & 1;
    const int fr = l & 15;
    const int fk = (l >> 4) * 8;
    const int srow = l >> 2;
    const int skel = (l & 3) * 8;

    f32x4 acc[4][4];
#pragma unroll
    for (int i = 0; i < 4; ++i)
#pragma unroll
        for (int j = 0; j < 4; ++j) acc[i][j] = (f32x4){0.f, 0.f, 0.f, 0.f};

    for (int k0 = 0; k0 < K; k0 += 32) {
#pragma unroll
        for (int c = 0; c < 2; ++c) {
            const int r0 = w * 32 + c * 16;
            gload16(A + (size_t)(m0 + r0 + srow) * lda + k0 + skel, &As[r0][0]);
            gload16(B + (size_t)(n0 + r0 + srow) * ldb + k0 + skel, &Bs[r0][0]);
        }
        __syncthreads();

        s16x8 af[4], bfg[4];
#pragma unroll
        for (int mi = 0; mi < 4; ++mi)
            af[mi] = *reinterpret_cast<const s16x8*>(&As[wr * 64 + mi * 16 + fr][fk]);
#pragma unroll
        for (int ni = 0; ni < 4; ++ni)
            bfg[ni] = *reinterpret_cast<const s16x8*>(&Bs[wc * 64 + ni * 16 + fr][fk]);
#pragma unroll
        for (int mi = 0; mi < 4; ++mi)
#pragma unroll
            for (int ni = 0; ni < 4; ++ni)
                acc[mi][ni] = __builtin_amdgcn_mfma_f32_16x16x32_bf16(
                    af[mi], bfg[ni], acc[mi][ni], 0, 0, 0);
        __syncthreads();
    }

#pragma unroll
    for (int mi = 0; mi < 4; ++mi) {
#pragma unroll
        for (int ni = 0; ni < 4; ++ni) {
            const int col = n0 + wc * 64 + ni * 16 + fr;
            float bs = BIAS ? bias[col] : 0.f;
            f32x4 v = acc[mi][ni];
#pragma unroll
            for (int r = 0; r < 4; ++r) {
                const int row = m0 + wr * 64 + mi * 16 + (l >> 4) * 4 + r;
                float val = v[r] + bs;
                if (ACT == 1) val = 0.5f * val * (1.0f + erff(val * 0.70710678118654752440f));
                size_t idx = (size_t)row * ldc + col;
                if (OUT == 0) {
                    if (ACC) val += Cf[idx];
                    Cf[idx] = val;
                } else {
                    Cb[idx] = f2bf(val);
                }
            }
        }
    }
}

// ----------------------------------------------------------------------------
// bf16 MFMA GEMM, 64x64 tile (CU-coverage variant for small-M GEMMs).
// ----------------------------------------------------------------------------
template<int ACT, bool ACC, bool BIAS, int OUT>
__global__ __launch_bounds__(256)
void gemm_bf16_t64(const unsigned short* __restrict__ A, const unsigned short* __restrict__ B,
                   const float* __restrict__ bias, float* __restrict__ Cf,
                   unsigned short* __restrict__ Cb,
                   int M, int N, int K, int lda, int ldb, int ldc)
{
    __shared__ alignas(16) unsigned short As[64][32];
    __shared__ alignas(16) unsigned short Bs[64][32];

    const int tid = threadIdx.x;
    const int m0 = blockIdx.y * 64;
    const int n0 = blockIdx.x * 64;
    const int l  = tid & 63;
    const int w  = tid >> 6;
    const int wr = w >> 1, wc = w & 1;
    const int fr = l & 15;
    const int fk = (l >> 4) * 8;

    f32x4 acc[2][2];
#pragma unroll
    for (int i = 0; i < 2; ++i)
#pragma unroll
        for (int j = 0; j < 2; ++j) acc[i][j] = (f32x4){0.f, 0.f, 0.f, 0.f};

    for (int k0 = 0; k0 < K; k0 += 32) {
        gload16(A + (size_t)(m0 + w * 16 + (l >> 2)) * lda + k0 + (l & 3) * 8, &As[w * 16][0]);
        gload16(B + (size_t)(n0 + w * 16 + (l >> 2)) * ldb + k0 + (l & 3) * 8, &Bs[w * 16][0]);
        __syncthreads();

        s16x8 af[2], bfg[2];
#pragma unroll
        for (int mi = 0; mi < 2; ++mi)
            af[mi] = *reinterpret_cast<const s16x8*>(&As[wr * 32 + mi * 16 + fr][fk]);
#pragma unroll
        for (int ni = 0; ni < 2; ++ni)
            bfg[ni] = *reinterpret_cast<const s16x8*>(&Bs[wc * 32 + ni * 16 + fr][fk]);
#pragma unroll
        for (int mi = 0; mi < 2; ++mi)
#pragma unroll
            for (int ni = 0; ni < 2; ++ni)
                acc[mi][ni] = __builtin_amdgcn_mfma_f32_16x16x32_bf16(
                    af[mi], bfg[ni], acc[mi][ni], 0, 0, 0);
        __syncthreads();
    }

#pragma unroll
    for (int mi = 0; mi < 2; ++mi) {
#pragma unroll
        for (int ni = 0; ni < 2; ++ni) {
            const int col = n0 + wc * 32 + ni * 16 + fr;
            float bs = BIAS ? bias[col] : 0.f;
            f32x4 v = acc[mi][ni];
#pragma unroll
            for (int r = 0; r < 4; ++r) {
                const int row = m0 + wr * 32 + mi * 16 + (l >> 4) * 4 + r;
                float val = v[r] + bs;
                if (ACT == 1) val = 0.5f * val * (1.0f + erff(val * 0.70710678118654752440f));
                size_t idx = (size_t)row * ldc + col;
                if (OUT == 0) {
                    if (ACC) val += Cf[idx];
                    Cf[idx] = val;
                } else {
                    Cb[idx] = f2bf(val);
                }
            }
        }
    }
}

// ----------------------------------------------------------------------------
// fp32 GEMM (small/sensitive): C = act(A*B^T + bias); optional K-split atomic.
// ----------------------------------------------------------------------------
template<int ACT, bool BIAS, bool ATOMIC>
__global__ __launch_bounds__(256)
void gemm_bt(const float* __restrict__ A, const float* __restrict__ B,
             const float* __restrict__ bias, float* __restrict__ C,
             int M, int N, int K, int lda, int ldb, int ldc, int ksplit)
{
    __shared__ alignas(16) float As[16][68];
    __shared__ alignas(16) float Bs[16][68];
    const int tid = threadIdx.x;
    const int m0 = blockIdx.y * 64;
    const int n0 = blockIdx.x * 64;
    const int ty = tid >> 4, tx = tid & 15;
    const int lrow = tid >> 2;
    const int lk   = (tid & 3) << 2;

    float acc[4][4] = {};
    const int kbeg = blockIdx.z * ksplit;
    const int kend = kbeg + ksplit;

    for (int k0 = kbeg; k0 < kend; k0 += 16) {
        {
            int gr = m0 + lrow;
            float4 v; v.x = v.y = v.z = v.w = 0.f;
            if (gr < M) v = *reinterpret_cast<const float4*>(A + (size_t)gr * lda + k0 + lk);
            As[lk + 0][lrow] = v.x; As[lk + 1][lrow] = v.y;
            As[lk + 2][lrow] = v.z; As[lk + 3][lrow] = v.w;
        }
        {
            int gr = n0 + lrow;
            float4 v; v.x = v.y = v.z = v.w = 0.f;
            if (gr < N) v = *reinterpret_cast<const float4*>(B + (size_t)gr * ldb + k0 + lk);
            Bs[lk + 0][lrow] = v.x; Bs[lk + 1][lrow] = v.y;
            Bs[lk + 2][lrow] = v.z; Bs[lk + 3][lrow] = v.w;
        }
        __syncthreads();
#pragma unroll
        for (int k = 0; k < 16; ++k) {
            float4 a = *reinterpret_cast<const float4*>(&As[k][ty << 2]);
            float4 b = *reinterpret_cast<const float4*>(&Bs[k][tx << 2]);
            acc[0][0] += a.x * b.x; acc[0][1] += a.x * b.y; acc[0][2] += a.x * b.z; acc[0][3] += a.x * b.w;
            acc[1][0] += a.y * b.x; acc[1][1] += a.y * b.y; acc[1][2] += a.y * b.z; acc[1][3] += a.y * b.w;
            acc[2][0] += a.z * b.x; acc[2][1] += a.z * b.y; acc[2][2] += a.z * b.z; acc[2][3] += a.z * b.w;
            acc[3][0] += a.w * b.x; acc[3][1] += a.w * b.y; acc[3][2] += a.w * b.z; acc[3][3] += a.w * b.w;
        }
        __syncthreads();
    }

#pragma unroll
    for (int i = 0; i < 4; ++i) {
        int m = m0 + (ty << 2) + i;
        if (m >= M) continue;
#pragma unroll
        for (int j = 0; j < 4; ++j) {
            int n = n0 + (tx << 2) + j;
            if (n >= N) continue;
            float v = acc[i][j];
            if (BIAS && blockIdx.z == 0) v += bias[n];
            if (ACT == 2) v = fmaxf(v, 0.f) + log1pf(expf(-fabsf(v)));
            size_t idx = (size_t)m * ldc + n;
            if (ATOMIC) atomicAdd(&C[idx], v);
            else C[idx] = v;
        }
    }
}

// ----------------------------------------------------------------------------
// LayerNorm (last dim 1024). OUT: 0 fp32, 1 bf16, 2 both.
// ----------------------------------------------------------------------------
template<bool RES, int OUT>
__global__ __launch_bounds__(256)
void ln_k(const float* __restrict__ x, const float* __restrict__ res,
          const float* __restrict__ g, const float* __restrict__ b,
          float* __restrict__ outf, unsigned short* __restrict__ outb)
{
    int row = blockIdx.x;
    int t = threadIdx.x;
    float4 v = reinterpret_cast<const float4*>(x + (size_t)row * 1024)[t];
    if (RES) {
        float4 r2 = reinterpret_cast<const float4*>(res + (size_t)row * 1024)[t];
        v.x += r2.x; v.y += r2.y; v.z += r2.z; v.w += r2.w;
    }
    float s  = v.x + v.y + v.z + v.w;
    float ss = v.x * v.x + v.y * v.y + v.z * v.z + v.w * v.w;
#pragma unroll
    for (int off = 32; off > 0; off >>= 1) {
        s  += __shfl_down(s, off, 64);
        ss += __shfl_down(ss, off, 64);
    }
    __shared__ float red[2][4];
    __shared__ float mv[2];
    int wid = t >> 6;
    if ((t & 63) == 0) { red[0][wid] = s; red[1][wid] = ss; }
    __syncthreads();
    if (t == 0) {
        float S  = red[0][0] + red[0][1] + red[0][2] + red[0][3];
        float SS = red[1][0] + red[1][1] + red[1][2] + red[1][3];
        float mean = S * (1.f / 1024.f);
        float var  = SS * (1.f / 1024.f) - mean * mean;
        mv[0] = mean; mv[1] = rsqrtf(var + 1e-5f);
    }
    __syncthreads();
    float mean = mv[0], rstd = mv[1];
    float4 gg = reinterpret_cast<const float4*>(g)[t];
    float4 bb = reinterpret_cast<const float4*>(b)[t];
    float y0 = (v.x - mean) * rstd * gg.x + bb.x;
    float y1 = (v.y - mean) * rstd * gg.y + bb.y;
    float y2 = (v.z - mean) * rstd * gg.z + bb.z;
    float y3 = (v.w - mean) * rstd * gg.w + bb.w;
    if (OUT == 0 || OUT == 2) {
        float4 ov; ov.x = y0; ov.y = y1; ov.z = y2; ov.w = y3;
        reinterpret_cast<float4*>(outf + (size_t)row * 1024)[t] = ov;
    }
    if (OUT == 1 || OUT == 2) {
        unsigned long long p = (unsigned long long)f2bf(y0)
                             | ((unsigned long long)f2bf(y1) << 16)
                             | ((unsigned long long)f2bf(y2) << 32)
                             | ((unsigned long long)f2bf(y3) << 48);
        *reinterpret_cast<unsigned long long*>(outb + (size_t)row * 1024 + t * 4) = p;
    }
}

// ----------------------------------------------------------------------------
// MFMA flash attention partials. grid 1024=(b,h,qsp,split4), blk 256 (4 waves).
// K/V from combined KV buffer, row stride 2048 (K cols 0..1023, V 1024..2047).
// Vt LDS uses XOR kblk swizzle; Ps padded to 20 -> conflict-free stores.
// ----------------------------------------------------------------------------
__global__ __launch_bounds__(256)
void attn_part_mfma(const unsigned short* __restrict__ qh,
                    const unsigned short* __restrict__ kv,
                    float* __restrict__ pacc, float* __restrict__ pml)
{
    const int bx = blockIdx.x;
    const int split = bx & 3;
    const int qsp = (bx >> 2) & 3;
    const int h = (bx >> 4) & 15;
    const int b = bx >> 8;
    const int tid = threadIdx.x;
    const int l = tid & 63, w = tid >> 6;
    const int g = l >> 4, q4 = l & 15;

    __shared__ alignas(16) unsigned short Ks[64][72];
    __shared__ alignas(16) unsigned short Vt[64][72];
    __shared__ alignas(16) unsigned short Ps[4][64][20];

    s16x8 qf[2];
    {
        const int qrow = qsp * 64 + w * 16 + q4;
        const unsigned short* qp = qh + (size_t)qrow * 1024 + h * 64 + g * 8;
        qf[0] = *reinterpret_cast<const s16x8*>(qp);
        qf[1] = *reinterpret_cast<const s16x8*>(qp + 32);
    }

    f32x4 oacc[4];
#pragma unroll
    for (int mi = 0; mi < 4; ++mi) oacc[mi] = (f32x4){0.f, 0.f, 0.f, 0.f};
    float m_run = -1e30f, l_run = 0.f;

    const unsigned short* khb = kv + ((size_t)b * 2048 + split * 512) * 2048 + h * 64;
    const unsigned short* vhb = khb + 1024;

    const int krow = tid >> 2, dcol = (tid & 3) << 4;

    for (int kt = 0; kt < 512; kt += 64) {
        __syncthreads();
        {
            const unsigned short* ksrc = khb + (size_t)(kt + krow) * 2048 + dcol;
            s16x8 k0 = *reinterpret_cast<const s16x8*>(ksrc);
            s16x8 k1 = *reinterpret_cast<const s16x8*>(ksrc + 8);
            *reinterpret_cast<s16x8*>(&Ks[krow][dcol]) = k0;
            *reinterpret_cast<s16x8*>(&Ks[krow][dcol + 8]) = k1;
            const unsigned short* vsrc = vhb + (size_t)(kt + krow) * 2048 + dcol;
            s16x8 v0 = *reinterpret_cast<const s16x8*>(vsrc);
            s16x8 v1 = *reinterpret_cast<const s16x8*>(vsrc + 8);
            // transposed store with kblk XOR swizzle: element (d, k=krow)
            const int kb = krow >> 3, klo = krow & 7;
#pragma unroll
            for (int ii = 0; ii < 8; ++ii) {
                int d0 = dcol + ii, d1 = dcol + 8 + ii;
                Vt[d0][((kb ^ ((d0 >> 3) & 7)) << 3) + klo] = (unsigned short)v0[ii];
                Vt[d1][((kb ^ ((d1 >> 3) & 7)) << 3) + klo] = (unsigned short)v1[ii];
            }
        }
        __syncthreads();

        f32x4 sacc[4];
#pragma unroll
        for (int mt = 0; mt < 4; ++mt) sacc[mt] = (f32x4){0.f, 0.f, 0.f, 0.f};
#pragma unroll
        for (int dc = 0; dc < 2; ++dc) {
#pragma unroll
            for (int mt = 0; mt < 4; ++mt) {
                s16x8 ka = *reinterpret_cast<const s16x8*>(&Ks[mt * 16 + q4][g * 8 + dc * 32]);
                sacc[mt] = __builtin_amdgcn_mfma_f32_16x16x32_bf16(ka, qf[dc], sacc[mt], 0, 0, 0);
            }
        }

        float p[16];
        float pmax = -1e30f;
#pragma unroll
        for (int mt = 0; mt < 4; ++mt)
#pragma unroll
            for (int r = 0; r < 4; ++r)
                pmax = fmaxf(pmax, sacc[mt][r] * 0.125f);
        pmax = fmaxf(pmax, __shfl_xor(pmax, 16));
        pmax = fmaxf(pmax, __shfl_xor(pmax, 32));
        float m_new = fmaxf(m_run, pmax);
        float sc_o = __expf(m_run - m_new);
        float lpart = 0.f;
#pragma unroll
        for (int mt = 0; mt < 4; ++mt)
#pragma unroll
            for (int r = 0; r < 4; ++r) {
                float pv = __expf(sacc[mt][r] * 0.125f - m_new);
                p[mt * 4 + r] = pv;
                lpart += pv;
            }
        lpart += __shfl_xor(lpart, 16);
        lpart += __shfl_xor(lpart, 32);
        l_run = l_run * sc_o + lpart;
        m_run = m_new;
#pragma unroll
        for (int mi = 0; mi < 4; ++mi)
#pragma unroll
            for (int r = 0; r < 4; ++r)
                oacc[mi][r] *= sc_o;

#pragma unroll
        for (int mt = 0; mt < 4; ++mt)
#pragma unroll
            for (int r = 0; r < 4; ++r)
                Ps[w][mt * 16 + g * 4 + r][q4] = f2bf(p[mt * 4 + r]);

#pragma unroll
        for (int kc = 0; kc < 2; ++kc) {
            s16x8 pb;
#pragma unroll
            for (int j = 0; j < 8; ++j)
                pb[j] = (short)Ps[w][kc * 32 + g * 8 + j][q4];
#pragma unroll
            for (int mi = 0; mi < 4; ++mi) {
                const int d = mi * 16 + q4;
                s16x8 va = *reinterpret_cast<const s16x8*>(
                    &Vt[d][((4 * kc + g) ^ ((d >> 3) & 7)) << 3]);
                oacc[mi] = __builtin_amdgcn_mfma_f32_16x16x32_bf16(va, pb, oacc[mi], 0, 0, 0);
            }
        }
    }

    const int rowg = (b * 16 + h) * 256 + qsp * 64 + w * 16 + q4;
    float* pa = pacc + ((size_t)split * 16384 + rowg) * 64;
#pragma unroll
    for (int mi = 0; mi < 4; ++mi)
        *reinterpret_cast<f32x4*>(pa + mi * 16 + g * 4) = oacc[mi];
    if (g == 0) {
        pml[((size_t)split * 16384 + rowg) * 2 + 0] = m_run;
        pml[((size_t)split * 16384 + rowg) * 2 + 1] = l_run;
    }
}

// combine 4 partials per q-row -> bf16 o
__global__ __launch_bounds__(64)
void attn_comb_k(const float* __restrict__ pacc, const float* __restrict__ pml,
                 unsigned short* __restrict__ o)
{
    int row = blockIdx.x * 64 + threadIdx.x;
    float M = -1e30f;
#pragma unroll
    for (int s = 0; s < 4; ++s)
        M = fmaxf(M, pml[((size_t)s * 16384 + row) * 2]);
    float L = 0.f;
    float out[64] = {};
#pragma unroll
    for (int s = 0; s < 4; ++s) {
        float ms = pml[((size_t)s * 16384 + row) * 2 + 0];
        float ls = pml[((size_t)s * 16384 + row) * 2 + 1];
        float wgt = __expf(ms - M);
        L += wgt * ls;
        const float4* ap = reinterpret_cast<const float4*>(pacc + ((size_t)s * 16384 + row) * 64);
#pragma unroll
        for (int d4 = 0; d4 < 16; ++d4) {
            float4 a = ap[d4];
            out[d4 * 4 + 0] += wgt * a.x; out[d4 * 4 + 1] += wgt * a.y;
            out[d4 * 4 + 2] += wgt * a.z; out[d4 * 4 + 3] += wgt * a.w;
        }
    }
    float inv = 1.f / L;
    int t = row & 63, qt = (row >> 6) & 3, h = (row >> 8) & 15, b = row >> 12;
    unsigned short* op = o + (size_t)(b * 256 + qt * 64 + t) * 1024 + h * 64;
#pragma unroll
    for (int d8 = 0; d8 < 8; ++d8) {
        s16x8 v;
#pragma unroll
        for (int j = 0; j < 8; ++j) v[j] = (short)f2bf(out[d8 * 8 + j] * inv);
        *reinterpret_cast<s16x8*>(op + d8 * 8) = v;
    }
}

// hq = qln[r%256] + op; writes fp32 + bf16
__global__ void add_bcast_k(const float* __restrict__ q, const float* __restrict__ o,
                            float* __restrict__ hq, unsigned short* __restrict__ hqb)
{
    int i = blockIdx.x * 256 + threadIdx.x;
    int r = i >> 8, c = i & 255;
    float4 qv = reinterpret_cast<const float4*>(q)[(r & 255) * 256 + c];
    float4 ov = reinterpret_cast<const float4*>(o)[i];
    float4 s; s.x = qv.x + ov.x; s.y = qv.y + ov.y; s.z = qv.z + ov.z; s.w = qv.w + ov.w;
    reinterpret_cast<float4*>(hq)[i] = s;
    unsigned long long p = (unsigned long long)f2bf(s.x)
                         | ((unsigned long long)f2bf(s.y) << 16)
                         | ((unsigned long long)f2bf(s.z) << 32)
                         | ((unsigned long long)f2bf(s.w) << 48);
    *reinterpret_cast<unsigned long long*>(hqb + (size_t)r * 1024 + c * 4) = p;
}

// causal depthwise conv (K=4) + bias + silu
__global__ void conv_k(const float* __restrict__ xz, const float* __restrict__ cw,
                       const float* __restrict__ cb, float* __restrict__ xc)
{
    int i = blockIdx.x * 256 + threadIdx.x;
    int r = i >> 11, c = i & 2047;
    int t = r & 255;
    float a = cb[c];
#pragma unroll
    for (int k = 0; k < 4; ++k) {
        int tt = t - 3 + k;
        if (tt >= 0) a += xz[(size_t)(r - 3 + k) * 4096 + c] * cw[c * 4 + k];
    }
    xc[i] = a / (1.f + expf(-a));
}

// ----------------------------------------------------------------------------
// mamba scan (16 segs x 16 steps, proven round 7) + fused gate epilogue:
// writes g = (y + D*xc) * silu(z) directly as bf16.
// ----------------------------------------------------------------------------
__global__ __launch_bounds__(256)
void scan_gate_k(const float* __restrict__ delta, const float* __restrict__ dbl,
                 const float* __restrict__ xc, const float* __restrict__ Alog,
                 const float* __restrict__ xz, const float* __restrict__ Dp,
                 unsigned short* __restrict__ gb)
{
    const int t = threadIdx.x;
    const int pi = t & 15, seg = t >> 4;
    const int pr = blockIdx.x * 16 + pi;
    const int c = pr & 2047, b = pr >> 11;

    float A[16];
#pragma unroll
    for (int n = 0; n < 16; ++n) A[n] = -expf(Alog[c * 16 + n]);
    const float Dc = Dp[c];

    __shared__ float HE[15][16][17];
    __shared__ float HU[15][16][17];

    if (seg < 15) {
        float h[16], E[16];
#pragma unroll
        for (int n = 0; n < 16; ++n) { h[n] = 0.f; E[n] = 1.f; }
        for (int s = 0; s < 16; ++s) {
            int r = b * 256 + seg * 16 + s;
            float dt = delta[(size_t)r * 2048 + c];
            float xv = xc[(size_t)r * 2048 + c];
            const float* row = dbl + (size_t)r * 96;
            float dx = dt * xv;
#pragma unroll
            for (int n = 0; n < 16; ++n) {
                float e = __expf(dt * A[n]);
                h[n] = e * h[n] + dx * row[64 + n];
                E[n] *= e;
            }
        }
#pragma unroll
        for (int n = 0; n < 16; ++n) { HE[seg][pi][n] = E[n]; HU[seg][pi][n] = h[n]; }
    }
    __syncthreads();

    float hs[16];
#pragma unroll
    for (int n = 0; n < 16; ++n) hs[n] = 0.f;
    for (int s2 = 0; s2 < seg; ++s2) {
#pragma unroll
        for (int n = 0; n < 16; ++n)
            hs[n] = HE[s2][pi][n] * hs[n] + HU[s2][pi][n];
    }

    for (int s = 0; s < 16; ++s) {
        int r = b * 256 + seg * 16 + s;
        float dt = delta[(size_t)r * 2048 + c];
        float xv = xc[(size_t)r * 2048 + c];
        const float* row = dbl + (size_t)r * 96;
        float dx = dt * xv;
        float y = 0.f;
#pragma unroll
        for (int n = 0; n < 16; ++n) {
            float e = __expf(dt * A[n]);
            hs[n] = e * hs[n] + dx * row[64 + n];
            y += hs[n] * row[80 + n];
        }
        float zv = xz[(size_t)r * 4096 + 2048 + c];
        float gv = (y + Dc * xv) * (zv / (1.f + expf(-zv)));
        gb[(size_t)r * 2048 + c] = f2bf(gv);
    }
}

// fp32 -> bf16 bulk convert, 8 elems/thread, n = grid*2048 exactly
__global__ __launch_bounds__(256)
void cvt_bf16_k(const float* __restrict__ in, unsigned short* __restrict__ out)
{
    size_t i = ((size_t)blockIdx.x * 256 + threadIdx.x) * 8;
    float4 a = *reinterpret_cast<const float4*>(in + i);
    float4 b = *reinterpret_cast<const float4*>(in + i + 4);
    s16x8 v;
    v[0] = (short)f2bf(a.x); v[1] = (short)f2bf(a.y);
    v[2] = (short)f2bf(a.z); v[3] = (short)f2bf(a.w);
    v[4] = (short)f2bf(b.x); v[5] = (short)f2bf(b.y);
    v[6] = (short)f2bf(b.z); v[7] = (short)f2bf(b.w);
    *reinterpret_cast<s16x8*>(out + i) = v;
}

__global__ void fill_ones_f32(float* p, int n)
{
    int i = blockIdx.x * 256 + threadIdx.x;
    if (i < n) p[i] = 1.0f;
}

__global__ void fill_zero_f32(float* p, int n)
{
    int i = blockIdx.x * 256 + threadIdx.x;
    if (i < n) p[i] = 0.0f;
}

extern "C" void kernel_launch(void* const* d_in, const int* in_sizes, int n_in,
                              void* d_out, int out_size, void* d_ws, size_t ws_size,
                              hipStream_t stream)
{
    const float* x      = (const float*)d_in[0];
    const float* W_in   = (const float*)d_in[2];
    const float* b_in   = (const float*)d_in[3];
    const float* latents= (const float*)d_in[4];
    const float* lnq_g  = (const float*)d_in[5];
    const float* lnq_b  = (const float*)d_in[6];
    const float* lnkv_g = (const float*)d_in[7];
    const float* lnkv_b = (const float*)d_in[8];
    const float* W_qkv  = (const float*)d_in[9];
    const float* b_qkv  = (const float*)d_in[10];
    const float* W_o    = (const float*)d_in[11];
    const float* b_o    = (const float*)d_in[12];
    const float* W1     = (const float*)d_in[13];
    const float* b1     = (const float*)d_in[14];
    const float* W2     = (const float*)d_in[15];
    const float* b2     = (const float*)d_in[16];
    const float* lnf_g  = (const float*)d_in[17];
    const float* lnf_b  = (const float*)d_in[18];
    const float* mb_ln_g= (const float*)d_in[19];
    const float* mb_ln_b= (const float*)d_in[20];
    const float* mb_Win = (const float*)d_in[21];
    const float* mb_cw  = (const float*)d_in[22];
    const float* mb_cb  = (const float*)d_in[23];
    const float* mb_xp  = (const float*)d_in[24];
    const float* mb_dtW = (const float*)d_in[25];
    const float* mb_dtb = (const float*)d_in[26];
    const float* mb_Alog= (const float*)d_in[27];
    const float* mb_D   = (const float*)d_in[28];
    const float* mb_Wout= (const float*)d_in[29];
    const float* enc_g  = (const float*)d_in[30];
    const float* enc_b  = (const float*)d_in[31];
    const float* out_g  = (const float*)d_in[32];
    const float* out_b  = (const float*)d_in[33];

    float* W = (float*)d_ws;
    typedef unsigned short us;
    // --- phase A: through attention ---
    float* kvh  = W + 0;           // h fp32 [8192x1024]; later pacc (4.2M fl)
    float* qln  = W + 25165824;    // 256x1024
    float* op   = W + 26738688;    // 1024x1024 (pml during attn)
    float* hq   = W + 27787264;    // 1024x1024 (persistent)
    us* P       = (us*)(W + 8388608);
    us* kv_bf   = P + 0;           // 8192x1024 (LN'd kv)
    us* KV      = P + 8388608;     // 8192x2048 combined K|V
    us* qh_bf   = P + 25165824;    // 256x1024
    us* Wqkv_bf = P + 25427968;    // 3145728
    us* Win_bf  = P + 28573696;    // 524288
    us* xbf     = P + 29097984;    // 4194304
    float* pacc = kvh;             // 4*16384*64 = 4194304 fl
    float* pml  = op;              // 131072 fl
    // --- phase A2 scratch (kvh region dead after attention reads) ---
    us* Wo_bf   = (us*)(W + 4194304);   // 1048576 shorts (after pacc)
    us* W1_bf   = (us*)(W + 4718592);   // 2097152
    us* W2_bf   = (us*)(W + 5767168);   // 2097152
    us* ff1_bf  = (us*)(W + 6815744);   // 2097152
    us* hq_bf   = (us*)(W + 7864320);   // 1048576 (ends 8388608)
    us* o_bf    = (us*)(W + 25690112);  // 1048576
    us* qln_bf  = (us*)(W + 26214400);  // 262144
    // --- phase B (mamba): weights hoisted into dead P region ---
    us* Win_all = (us*)(W + 8388608);   // 16777216 shorts
    us* Wout_all= (us*)(W + 16777216);  // 8388608 shorts
    us* u_bf    = (us*)(W + 0);         // 1048576 shorts
    float* xz   = W + 524288;           // 4194304 fl
    float* xc   = W + 4718592;          // 2097152 fl
    float* dbl  = W + 6815744;          // 98304 fl
    float* dly  = W + 20971520;         // 2097152 fl
    us* gb_bf   = (us*)(W + 23068672);  // 2097152 shorts
    float* tmp  = W + 26214400;         // 1048576 fl

    dim3 blk(256);

    cvt_bf16_k<<<2048,blk,0,stream>>>(x, xbf);
    cvt_bf16_k<<<256,blk,0,stream>>>(W_in, Win_bf);
    cvt_bf16_k<<<1536,blk,0,stream>>>(W_qkv, Wqkv_bf);
    // 1. h = x @ W_in^T + b_in
    gemm_bf16<0,false,true,0><<<dim3(8,64),blk,0,stream>>>(xbf, Win_bf, b_in, kvh, nullptr, 8192,1024,512, 512,512,1024);
    // 2. kv = LN(h) -> bf16
    ln_k<false,1><<<8192,blk,0,stream>>>(kvh, nullptr, lnkv_g, lnkv_b, nullptr, kv_bf);
    // 3. qln = LN(latents)
    ln_k<false,2><<<256,blk,0,stream>>>(latents, nullptr, lnq_g, lnq_b, qln, qln_bf);
    // 4. q projection
    gemm_bf16_t64<0,false,true,1><<<dim3(16,4),blk,0,stream>>>(qln_bf, Wqkv_bf, b_qkv, nullptr, qh_bf, 256,1024,1024, 1024,1024,1024);
    // 5. fused K|V projection (Wk,Wv contiguous rows) -> KV[8192][2048]
    gemm_bf16<0,false,true,1><<<dim3(16,64),blk,0,stream>>>(kv_bf, Wqkv_bf+1048576, b_qkv+1024, nullptr, KV, 8192,2048,1024, 1024,1024,2048);
    // 7. attention (4-way KV split + combine)
    attn_part_mfma<<<1024,blk,0,stream>>>(qh_bf, KV, pacc, pml);
    cvt_bf16_k<<<512,blk,0,stream>>>(W_o, Wo_bf);
    attn_comb_k<<<256,64,0,stream>>>(pacc, pml, o_bf);
    // 8. o proj
    gemm_bf16_t64<0,false,true,0><<<dim3(16,16),blk,0,stream>>>(o_bf, Wo_bf, b_o, op, nullptr, 1024,1024,1024, 1024,1024,1024);
    // 9. hq = q + op
    add_bcast_k<<<1024,blk,0,stream>>>(qln, op, hq, hq_bf);
    // 10-11. FFN
    cvt_bf16_k<<<1024,blk,0,stream>>>(W1, W1_bf);
    cvt_bf16_k<<<1024,blk,0,stream>>>(W2, W2_bf);
    gemm_bf16_t64<1,false,true,1><<<dim3(32,16),blk,0,stream>>>(hq_bf, W1_bf, b1, nullptr, ff1_bf, 1024,2048,1024, 1024,1024,2048);
    gemm_bf16_t64<0,false,true,0><<<dim3(16,16),blk,0,stream>>>(ff1_bf, W2_bf, b2, tmp, nullptr, 1024,1024,2048, 2048,2048,1024);
    // 12. hq = LN(hq + ff2)
    ln_k<true,0><<<1024,blk,0,stream>>>(hq, tmp, lnf_g, lnf_b, hq, nullptr);
    // hoisted mamba weight conversion
    cvt_bf16_k<<<8192,blk,0,stream>>>(mb_Win, Win_all);
    cvt_bf16_k<<<4096,blk,0,stream>>>(mb_Wout, Wout_all);
    // 13. mamba blocks
    for (int i = 0; i < 4; ++i) {
        ln_k<false,1><<<1024,blk,0,stream>>>(hq, nullptr, mb_ln_g + i*1024, mb_ln_b + i*1024, nullptr, u_bf);
        gemm_bf16<0,false,false,0><<<dim3(32,8),blk,0,stream>>>(u_bf, Win_all + (size_t)i*4194304, nullptr, xz, nullptr, 1024,4096,1024, 1024,1024,4096);
        conv_k<<<8192,blk,0,stream>>>(xz, mb_cw + i*8192, mb_cb + i*2048, xc);
        fill_zero_f32<<<384,blk,0,stream>>>(dbl, 98304);
        gemm_bt<0,false,true><<<dim3(2,16,8),blk,0,stream>>>(xc, mb_xp + i*196608, nullptr, dbl, 1024,96,2048, 2048,2048,96, 256);
        gemm_bt<2,true,false><<<dim3(32,16,1),blk,0,stream>>>(dbl, mb_dtW + i*131072, mb_dtb + i*2048, dly, 1024,2048,64, 96,64,2048, 64);
        scan_gate_k<<<512,blk,0,stream>>>(dly, dbl, xc, mb_Alog + i*32768, xz, mb_D + i*2048, gb_bf);
        gemm_bf16_t64<0,true,false,0><<<dim3(16,16),blk,0,stream>>>(gb_bf, Wout_all + (size_t)i*2097152, nullptr, hq, nullptr, 1024,1024,2048, 2048,2048,1024);
    }
    // 14-15. final LNs
    ln_k<false,0><<<1024,blk,0,stream>>>(hq, nullptr, enc_g, enc_b, tmp, nullptr);
    ln_k<false,0><<<1024,blk,0,stream>>>(tmp, nullptr, out_g, out_b, (float*)d_out, nullptr);
    // 16. comp_mask = ones
    fill_ones_f32<<<4,blk,0,stream>>>((float*)d_out + 1048576, 1024);
}